// Round 13
// baseline (1003.179 us; speedup 1.0000x reference)
//
#include <hip/hip_runtime.h>
#include <hip/hip_bf16.h>
#include <math.h>

#define B_ 32
#define N_ 784
#define C_ 576
#define H_ 28
#define W_ 28
#define HEADS_ 8
#define HD_ 72
#define AGENT_ 49
#define M_ (B_ * N_)            // 25088
#define KTOT_ 5184              // 576 silu + 576*8 spline
#define QKVW_ 1728
#define SCALE_ 0.11785113019775793f

// BK=64 swizzled LDS: row stride 64 elems (128 B); 16B chunks XOR'd by row&7.
// Verified conflict-free (rounds 7-12: SQ_LDS_BANK_CONFLICT = 0).
#define SWZ64(row, chunk) (((row) << 6) + ((((chunk) ^ ((row) & 7))) << 3))

typedef unsigned short ushort_t;
typedef __attribute__((ext_vector_type(8))) unsigned short u16x8;
typedef __attribute__((ext_vector_type(8))) __bf16 bf16x8;
typedef __attribute__((ext_vector_type(4))) float f32x4;
typedef __attribute__((ext_vector_type(4))) unsigned u32x4;

__device__ __forceinline__ ushort_t f2bf(float f) {
  union { float f; unsigned u; } v; v.f = f;
  unsigned r = v.u + 0x7fffu + ((v.u >> 16) & 1u);
  return (ushort_t)(r >> 16);
}
__device__ __forceinline__ float bf2f(ushort_t u) {
  union { unsigned u; float f; } v; v.u = ((unsigned)u) << 16;
  return v.f;
}
__device__ __forceinline__ unsigned pack2(float lo, float hi) {
  __bf16 a = (__bf16)lo, b = (__bf16)hi;
  unsigned short ua = __builtin_bit_cast(unsigned short, a);
  unsigned short ub = __builtin_bit_cast(unsigned short, b);
  return (unsigned)ua | ((unsigned)ub << 16);
}
// async global->LDS, 16B per lane; LDS dest = base + lane*16 (linear)
__device__ __forceinline__ void gload16(const ushort_t* g, ushort_t* l) {
  __builtin_amdgcn_global_load_lds(
      (const __attribute__((address_space(1))) unsigned*)g,
      (__attribute__((address_space(3))) unsigned*)l, 16, 0, 0);
}

__device__ __forceinline__ u16x8 packf8(f32x4 a, f32x4 b) {
  u16x8 o;
  o[0]=f2bf(a[0]); o[1]=f2bf(a[1]); o[2]=f2bf(a[2]); o[3]=f2bf(a[3]);
  o[4]=f2bf(b[0]); o[5]=f2bf(b[1]); o[6]=f2bf(b[2]); o[7]=f2bf(b[3]);
  return o;
}

// ---------------- converts / packs ----------------
// x image: [196 m-tiles][9 k-win][128x64 swz]  (8192 elems per (tile,kwin))
__global__ __launch_bounds__(256) void convert_x_kernel(
    const float* __restrict__ x, ushort_t* __restrict__ xbt) {
  const int totalg = 196 * 9 * 1024;
  for (int g = blockIdx.x * 256 + threadIdx.x; g < totalg; g += gridDim.x * 256) {
    int tile = g >> 10, gi = g & 1023;
    int r = gi >> 3, chp = gi & 7;
    int ch = chp ^ (r & 7);
    int row = (tile / 9) * 128 + r;
    int k0 = (tile % 9) * 64 + ch * 8;
    const float* xp = x + (size_t)row * C_ + k0;
    f32x4 a = *(const f32x4*)xp;
    f32x4 b = *(const f32x4*)(xp + 4);
    *(u16x8*)(xbt + (size_t)tile * 8192 + gi * 8) = packf8(a, b);
  }
}

// W image: [9 n-tiles][9 k-win][192x64 swz] (12288 elems per (tile,kwin))
__global__ __launch_bounds__(256) void pack_w_kernel(
    const float* __restrict__ Wq, const float* __restrict__ Wkv,
    ushort_t* __restrict__ wbt) {
  int tile = blockIdx.x;             // 0..80
  int nt = tile / 9, kw = tile % 9;
  for (int gi = threadIdx.x; gi < 1536; gi += 256) {
    int r = gi >> 3, chp = gi & 7;
    int ch = chp ^ (r & 7);
    int j = nt * 192 + r;
    int k0 = kw * 64 + ch * 8;
    const float* wp = (j < C_) ? (Wq + (size_t)j * C_ + k0)
                               : (Wkv + (size_t)(j - C_) * C_ + k0);
    f32x4 a = *(const f32x4*)wp;
    f32x4 b = *(const f32x4*)(wp + 4);
    *(u16x8*)(wbt + (size_t)tile * 12288 + gi * 8) = packf8(a, b);
  }
}

// KAN B: plain row-major [o][KTOT] bf16 (read directly to MFMA fragments)
__global__ __launch_bounds__(256) void pack_b_kernel(
    const float* __restrict__ base_w, const float* __restrict__ spline_w,
    const float* __restrict__ spline_s, ushort_t* __restrict__ bpackb) {
  int o = blockIdx.x;
  for (int j = threadIdx.x; j < KTOT_; j += 256) {
    float v;
    if (j < C_) {
      v = base_w[(size_t)o * C_ + j];
    } else {
      int jj = j - C_;
      int i = jj >> 3, kk = jj & 7;
      v = spline_w[((size_t)o * C_ + i) * 8 + kk] * spline_s[(size_t)o * C_ + i];
    }
    bpackb[(size_t)o * KTOT_ + j] = f2bf(v);
  }
}

// ---------------- bias precompute ----------------
__device__ __forceinline__ float bilerp7(const float* __restrict__ Bsrc, int y, int x) {
  float sy = y * 0.25f - 0.375f;
  float sx = x * 0.25f - 0.375f;
  float fy0 = floorf(sy), fx0 = floorf(sx);
  int y0 = (int)fy0, x0 = (int)fx0;
  float fy = sy - fy0, fx = sx - fx0;
  int y0c = min(6, max(0, y0)), y1c = min(6, max(0, y0 + 1));
  int x0c = min(6, max(0, x0)), x1c = min(6, max(0, x0 + 1));
  float v00 = Bsrc[y0c * 7 + x0c], v01 = Bsrc[y0c * 7 + x1c];
  float v10 = Bsrc[y1c * 7 + x0c], v11 = Bsrc[y1c * 7 + x1c];
  return (1.f - fy) * ((1.f - fx) * v00 + fx * v01)
       + fy * ((1.f - fx) * v10 + fx * v11);
}

__global__ __launch_bounds__(256) void bias_kernel(
    const float* __restrict__ an_bias, const float* __restrict__ na_bias,
    const float* __restrict__ ah_bias, const float* __restrict__ aw_bias,
    const float* __restrict__ ha_bias, const float* __restrict__ wa_bias,
    float* __restrict__ abias, float* __restrict__ qbias) {
  int idx = blockIdx.x * 256 + threadIdx.x;
  if (idx >= HEADS_ * AGENT_ * N_) return;
  int n = idx % N_;
  int ha = idx / N_;
  int h = ha / AGENT_, a = ha % AGENT_;
  int y = n / W_, x = n % W_;
  float pb1 = bilerp7(an_bias + (size_t)ha * 49, y, x);
  float pb2 = ah_bias[ha * H_ + y] + aw_bias[ha * W_ + x];
  abias[(size_t)ha * N_ + n] = pb1 + pb2;
  float ab1 = bilerp7(na_bias + (size_t)ha * 49, y, x);
  float ab2 = ha_bias[(h * H_ + y) * AGENT_ + a] + wa_bias[(h * W_ + x) * AGENT_ + a];
  qbias[((size_t)h * N_ + n) * AGENT_ + a] = ab1 + ab2;
}

// ---------------- MFMA GEMM: qkv (8 waves, BK=64, global_load_lds) ---------
// grid: 1764 = 196 row-tiles x 9 col-tiles (col fastest); 1764 = 8*220+4
__global__ __launch_bounds__(512, 4) void mfma_qkv_kernel(
    const ushort_t* __restrict__ At, const ushort_t* __restrict__ Bt,
    ushort_t* __restrict__ out) {
  __shared__ ushort_t Asl[2][128 * 64];   // 32 KB
  __shared__ ushort_t Bsl[2][192 * 64];   // 48 KB
  const int tid = threadIdx.x;
  const int lane = tid & 63, wid = tid >> 6;
  const int wm = wid >> 2, wn = wid & 3;
  const int l16 = lane & 15, lq = lane >> 4;

  int lin = blockIdx.x;
  const int q = 220, r = 4;          // 1764 = 8*220+4
  int xcd = lin & 7;
  int wg = (xcd < r ? xcd * (q + 1) : r * (q + 1) + (xcd - r) * q) + (lin >> 3);
  const int m0 = (wg / 9) * 128, n0 = (wg % 9) * 192;

  const ushort_t* aimg = At + (size_t)(wg / 9) * 9 * 8192;
  const ushort_t* bimg = Bt + (size_t)(wg % 9) * 9 * 12288;
  const int aslot = wid * 2;
  const int bslot = wid * 3;

  #pragma unroll
  for (int u = 0; u < 2; ++u)
    gload16(aimg + (size_t)(aslot + u) * 512 + lane * 8, &Asl[0][(aslot + u) * 512]);
  #pragma unroll
  for (int u = 0; u < 3; ++u)
    gload16(bimg + (size_t)(bslot + u) * 512 + lane * 8, &Bsl[0][(bslot + u) * 512]);
  __syncthreads();

  f32x4 acc[4][3] = {};
  const int NSTEP = C_ / 64;   // 9
  for (int s = 0; s < NSTEP; ++s) {
    const int cur = s & 1;
    if (s + 1 < NSTEP) {
      const int nxt = cur ^ 1;
      const ushort_t* ai = aimg + (size_t)(s + 1) * 8192;
      const ushort_t* bi = bimg + (size_t)(s + 1) * 12288;
      #pragma unroll
      for (int u = 0; u < 2; ++u)
        gload16(ai + (size_t)(aslot + u) * 512 + lane * 8, &Asl[nxt][(aslot + u) * 512]);
      #pragma unroll
      for (int u = 0; u < 3; ++u)
        gload16(bi + (size_t)(bslot + u) * 512 + lane * 8, &Bsl[nxt][(bslot + u) * 512]);
    }
    #pragma unroll
    for (int ks = 0; ks < 2; ++ks) {
      bf16x8 af[4], bfr[3];
      #pragma unroll
      for (int fm = 0; fm < 4; ++fm)
        af[fm] = *(const bf16x8*)&Asl[cur][SWZ64(wm * 64 + fm * 16 + l16, ks * 4 + lq)];
      #pragma unroll
      for (int fn = 0; fn < 3; ++fn)
        bfr[fn] = *(const bf16x8*)&Bsl[cur][SWZ64(wn * 48 + fn * 16 + l16, ks * 4 + lq)];
      #pragma unroll
      for (int fm = 0; fm < 4; ++fm)
        #pragma unroll
        for (int fn = 0; fn < 3; ++fn)
          acc[fm][fn] = __builtin_amdgcn_mfma_f32_16x16x32_bf16(
              af[fm], bfr[fn], acc[fm][fn], 0, 0, 0);
    }
    __syncthreads();
  }
  #pragma unroll
  for (int fm = 0; fm < 4; ++fm) {
    #pragma unroll
    for (int fn = 0; fn < 3; ++fn) {
      int col = n0 + wn * 48 + fn * 16 + l16;
      #pragma unroll
      for (int r2 = 0; r2 < 4; ++r2) {
        int row = m0 + wm * 64 + fm * 16 + lq * 4 + r2;
        out[(size_t)row * QKVW_ + col] = f2bf(acc[fm][fn][r2]);
      }
    }
  }
}

// ---------------- KAN A-operand generation (funnel-shift placement) --------
__device__ __forceinline__ u32x4 basesPack(float xv) {
  float s = __fmaf_rn(xv, 2.5f, 5.5f);
  float tf = floorf(s);
  int t = (int)tf;
  float u = s - tf;
  float u2 = u * u, u3 = u2 * u, um = 1.f - u;
  float p0 = u3 * (1.f / 6.f);
  float p1 = __fmaf_rn(u3, -0.5f, __fmaf_rn(u2, 0.5f, __fmaf_rn(u, 0.5f, 1.f / 6.f)));
  float p2 = __fmaf_rn(u3, 0.5f, __fmaf_rn(u2, -1.f, 2.f / 3.f));
  float p3 = um * um * um * (1.f / 6.f);
  unsigned lo = pack2(p3, p2);
  unsigned hi = pack2(p1, p0);
  unsigned long long packed = ((unsigned long long)hi << 32) | (unsigned long long)lo;
  int sh = t - 3;
  int ba = sh << 4;
  unsigned long long shl_lo = packed << (ba & 63);
  unsigned long long shr_sp = packed >> ((64 - ba) & 63);
  unsigned long long shl_hi = packed << ((ba - 64) & 63);
  unsigned long long shr_ng = packed >> ((-ba) & 63);
  unsigned long long Olo = (sh < 0) ? shr_ng : ((sh < 4) ? shl_lo : 0ull);
  unsigned long long Ohi = (sh <= 0) ? 0ull : ((sh < 4) ? shr_sp : shl_hi);
  if (t < 0 || t > 10) { Olo = 0ull; Ohi = 0ull; }
  u32x4 o;
  o[0] = (unsigned)Olo; o[1] = (unsigned)(Olo >> 32);
  o[2] = (unsigned)Ohi; o[3] = (unsigned)(Ohi >> 32);
  return o;
}

__device__ __forceinline__ u32x4 siluPack(const float* xv) {
  u32x4 o;
  #pragma unroll
  for (int e = 0; e < 4; ++e) {
    float v0 = xv[2 * e], v1 = xv[2 * e + 1];
    float s0 = v0 / (1.f + __expf(-v0));
    float s1 = v1 / (1.f + __expf(-v1));
    o[e] = pack2(s0, s1);
  }
  return o;
}

// ---------------- KAN MFMA GEMM (8 waves, BK=64, B direct-to-register) -----
// A staged in LDS (swizzled); B fragments loaded straight from L2/L3-resident
// row-major Bt with 1-step register prefetch. LDS traffic/step: 152KB -> 80KB.
// grid: 588 = 196 row-tiles x 3 col-tiles (col fastest); 588 = 8*73+4
__global__ __launch_bounds__(512, 4) void kan_mfma_kernel(
    const float* __restrict__ xf, const ushort_t* __restrict__ Bt,
    float* __restrict__ out) {
  __shared__ ushort_t Asl[2][128 * 64];   // 16 KB x2
  const int tid = threadIdx.x;
  const int lane = tid & 63, wid = tid >> 6;
  const int wm = wid >> 2, wn = wid & 3;
  const int l16 = lane & 15, lq = lane >> 4;

  int lin = blockIdx.x;
  const int q = 73, r = 4;           // 588 = 8*73+4
  int xcd = lin & 7;
  int wg = (xcd < r ? xcd * (q + 1) : r * (q + 1) + (xcd - r) * q) + (lin >> 3);
  const int m0 = (wg / 3) * 128, n0 = (wg % 3) * 192;

  const int srowi = tid >> 3;        // 0..63
  const int chk = tid & 7;           // 0..7

  const float* xfr0 = xf + (size_t)(m0 + srowi) * C_;
  const float* xfr1 = xfr0 + (size_t)64 * C_;
  // B fragment base pointers: one per fn, advanced by k offsets
  const ushort_t* bp0 = Bt + (size_t)(n0 + wn * 48 + l16) * KTOT_ + lq * 8;
  const ushort_t* bp1 = bp0 + (size_t)16 * KTOT_;
  const ushort_t* bp2 = bp0 + (size_t)32 * KTOT_;

  const int aW0 = SWZ64(srowi, chk), aW1 = SWZ64(srowi + 64, chk);

  f32x4 acc[4][3] = {};
  float xv0[8], xv1[8];
  u16x8 bcur[2][3], bnxt[2][3];

  // prologue: B(0) fragments; gen+write A(0); xv for step1
  #pragma unroll
  for (int ks = 0; ks < 2; ++ks) {
    bcur[ks][0] = *(const u16x8*)(bp0 + ks * 32);
    bcur[ks][1] = *(const u16x8*)(bp1 + ks * 32);
    bcur[ks][2] = *(const u16x8*)(bp2 + ks * 32);
  }
  {
    f32x4 a = *(const f32x4*)(xfr0 + chk * 8);
    f32x4 b = *(const f32x4*)(xfr0 + chk * 8 + 4);
    xv0[0]=a[0]; xv0[1]=a[1]; xv0[2]=a[2]; xv0[3]=a[3];
    xv0[4]=b[0]; xv0[5]=b[1]; xv0[6]=b[2]; xv0[7]=b[3];
    f32x4 c = *(const f32x4*)(xfr1 + chk * 8);
    f32x4 d = *(const f32x4*)(xfr1 + chk * 8 + 4);
    xv1[0]=c[0]; xv1[1]=c[1]; xv1[2]=c[2]; xv1[3]=c[3];
    xv1[4]=d[0]; xv1[5]=d[1]; xv1[6]=d[2]; xv1[7]=d[3];
  }
  *(u32x4*)&Asl[0][aW0] = siluPack(xv0);
  *(u32x4*)&Asl[0][aW1] = siluPack(xv1);
  {
    f32x4 a = *(const f32x4*)(xfr0 + 64 + chk * 8);
    f32x4 b = *(const f32x4*)(xfr0 + 64 + chk * 8 + 4);
    xv0[0]=a[0]; xv0[1]=a[1]; xv0[2]=a[2]; xv0[3]=a[3];
    xv0[4]=b[0]; xv0[5]=b[1]; xv0[6]=b[2]; xv0[7]=b[3];
    f32x4 c = *(const f32x4*)(xfr1 + 64 + chk * 8);
    f32x4 d = *(const f32x4*)(xfr1 + 64 + chk * 8 + 4);
    xv1[0]=c[0]; xv1[1]=c[1]; xv1[2]=c[2]; xv1[3]=c[3];
    xv1[4]=d[0]; xv1[5]=d[1]; xv1[6]=d[2]; xv1[7]=d[3];
  }
  __syncthreads();

  const int NSTEP = KTOT_ / 64;   // 81
  for (int s = 0; s < NSTEP; ++s) {
    const int cur = s & 1;
    if (s + 1 < NSTEP) {
      const int nxt = cur ^ 1;
      const int kn = (s + 1) * 64;
      // B(s+1) fragment prefetch (L2-resident; lands during MFMA below)
      #pragma unroll
      for (int ks = 0; ks < 2; ++ks) {
        bnxt[ks][0] = *(const u16x8*)(bp0 + kn + ks * 32);
        bnxt[ks][1] = *(const u16x8*)(bp1 + kn + ks * 32);
        bnxt[ks][2] = *(const u16x8*)(bp2 + kn + ks * 32);
      }
      // A(s+1): gen + ds_write nxt
      u32x4 a0, a1;
      if (kn < C_) { a0 = siluPack(xv0); a1 = siluPack(xv1); }
      else         { a0 = basesPack(xv0[0]); a1 = basesPack(xv1[0]); }
      *(u32x4*)&Asl[nxt][aW0] = a0;
      *(u32x4*)&Asl[nxt][aW1] = a1;
      // xv loads for s+2
      if (s + 2 < NSTEP) {
        const int kl = (s + 2) * 64;
        if (kl < C_) {
          f32x4 a = *(const f32x4*)(xfr0 + kl + chk * 8);
          f32x4 b = *(const f32x4*)(xfr0 + kl + chk * 8 + 4);
          xv0[0]=a[0]; xv0[1]=a[1]; xv0[2]=a[2]; xv0[3]=a[3];
          xv0[4]=b[0]; xv0[5]=b[1]; xv0[6]=b[2]; xv0[7]=b[3];
          f32x4 c = *(const f32x4*)(xfr1 + kl + chk * 8);
          f32x4 d = *(const f32x4*)(xfr1 + kl + chk * 8 + 4);
          xv1[0]=c[0]; xv1[1]=c[1]; xv1[2]=c[2]; xv1[3]=c[3];
          xv1[4]=d[0]; xv1[5]=d[1]; xv1[6]=d[2]; xv1[7]=d[3];
        } else {
          int i0 = ((kl - C_) >> 3) + chk;
          xv0[0] = xfr0[i0];
          xv1[0] = xfr1[i0];
        }
      }
    }
    // MFMA on cur: A from LDS, B from registers
    #pragma unroll
    for (int ks = 0; ks < 2; ++ks) {
      bf16x8 af[4];
      #pragma unroll
      for (int fm = 0; fm < 4; ++fm)
        af[fm] = *(const bf16x8*)&Asl[cur][SWZ64(wm * 64 + fm * 16 + l16, ks * 4 + lq)];
      #pragma unroll
      for (int fm = 0; fm < 4; ++fm)
        #pragma unroll
        for (int fn = 0; fn < 3; ++fn)
          acc[fm][fn] = __builtin_amdgcn_mfma_f32_16x16x32_bf16(
              af[fm], __builtin_bit_cast(bf16x8, bcur[ks][fn]), acc[fm][fn], 0, 0, 0);
    }
    __syncthreads();
    if (s + 1 < NSTEP) {
      #pragma unroll
      for (int ks = 0; ks < 2; ++ks)
        #pragma unroll
        for (int fn = 0; fn < 3; ++fn)
          bcur[ks][fn] = bnxt[ks][fn];
    }
  }
  #pragma unroll
  for (int fm = 0; fm < 4; ++fm) {
    #pragma unroll
    for (int fn = 0; fn < 3; ++fn) {
      int col = n0 + wn * 48 + fn * 16 + l16;
      #pragma unroll
      for (int r2 = 0; r2 < 4; ++r2) {
        int row = m0 + wm * 64 + fm * 16 + lq * 4 + r2;
        out[(size_t)row * C_ + col] = acc[fm][fn][r2];
      }
    }
  }
}

// ---------------- agent pooling ----------------
__global__ __launch_bounds__(576) void agent_pool_kernel(
    const ushort_t* __restrict__ qkvb, float* __restrict__ agent) {
  int ba = blockIdx.x;
  int b = ba / AGENT_, a = ba % AGENT_;
  int ay = a / 7, ax = a % 7;
  int ch = threadIdx.x;
  float s = 0.f;
  #pragma unroll
  for (int i2 = 0; i2 < 4; ++i2)
    #pragma unroll
    for (int i4 = 0; i4 < 4; ++i4)
      s += bf2f(qkvb[((size_t)b * N_ + (ay * 4 + i2) * W_ + (ax * 4 + i4)) * QKVW_ + ch]);
  agent[(size_t)ba * C_ + ch] = s * 0.0625f;
}

// ---------------- agent attention v3: MFMA flash, one block per (b,h) -------
#define AKS_ 104
#define VTS_ 136
__global__ __launch_bounds__(256) void agent_attn_mfma_kernel(
    const float* __restrict__ agent, const ushort_t* __restrict__ qkvb,
    const float* __restrict__ abias, float* __restrict__ agent_v) {
  __shared__ ushort_t A_lds[64 * AKS_];
  __shared__ ushort_t K_lds[112 * AKS_];
  __shared__ ushort_t Vt_lds[80 * VTS_];
  __shared__ ushort_t P_lds[4][16 * VTS_];
  const int tid = threadIdx.x;
  const int lane = tid & 63, wid = tid >> 6;
  const int l16 = lane & 15, lq = lane >> 4;
  const int b = blockIdx.x >> 3, h = blockIdx.x & 7;

  for (int i = tid; i < 64 * AKS_; i += 256) A_lds[i] = 0;
  for (int i = tid; i < 112 * 32; i += 256) {
    int r = i >> 5, cc = 72 + (i & 31);
    K_lds[r * AKS_ + cc] = 0;
  }
  for (int i = tid; i < 80 * VTS_; i += 256) Vt_lds[i] = 0;
  for (int i = tid; i < 4 * 16 * 24; i += 256) {
    int w = i / (16 * 24), rest = i % (16 * 24);
    int r = rest / 24, cc = 112 + rest % 24;
    P_lds[w][r * VTS_ + cc] = 0;
  }
  for (int i = tid; i < AGENT_ * HD_; i += 256) {
    int a = i / HD_, d = i % HD_;
    A_lds[a * AKS_ + d] = f2bf(agent[((size_t)b * AGENT_ + a) * C_ + h * HD_ + d]);
  }

  int srow[4], scol[4]; bool sval[4];
  #pragma unroll
  for (int i = 0; i < 4; ++i) {
    int idx = tid + i * 256;
    srow[i] = idx / 9; scol[i] = idx % 9;
    sval[i] = idx < 1008;
  }
  const ushort_t* kbase = qkvb + (size_t)b * N_ * QKVW_ + C_ + h * HD_;
  const ushort_t* vbase = qkvb + (size_t)b * N_ * QKVW_ + 2 * C_ + h * HD_;

  u16x8 kreg[4], vreg[4];
  #pragma unroll
  for (int i = 0; i < 4; ++i) {
    if (sval[i]) {
      kreg[i] = *(const u16x8*)(kbase + (size_t)srow[i] * QKVW_ + scol[i] * 8);
      vreg[i] = *(const u16x8*)(vbase + (size_t)srow[i] * QKVW_ + scol[i] * 8);
    }
  }
  #pragma unroll
  for (int i = 0; i < 4; ++i) {
    if (sval[i]) {
      *(u16x8*)&K_lds[srow[i] * AKS_ + scol[i] * 8] = kreg[i];
      #pragma unroll
      for (int e = 0; e < 8; ++e)
        Vt_lds[(scol[i] * 8 + e) * VTS_ + srow[i]] = vreg[i][e];
    }
  }
  __syncthreads();

  float m_r[4] = {-1e30f, -1e30f, -1e30f, -1e30f};
  float l_r[4] = {};
  f32x4 O[5] = {};
  const float* bias_base[4];
  #pragma unroll
  for (int r = 0; r < 4; ++r) {
    int a = wid * 16 + lq * 4 + r;
    a = min(a, AGENT_ - 1);
    bias_base[r] = abias + ((size_t)h * AGENT_ + a) * N_;
  }

  for (int c = 0; c < 7; ++c) {
    if (c < 6) {
      const size_t off = (size_t)(c + 1) * 112 * QKVW_;
      #pragma unroll
      for (int i = 0; i < 4; ++i) {
        if (sval[i]) {
          kreg[i] = *(const u16x8*)(kbase + off + (size_t)srow[i] * QKVW_ + scol[i] * 8);
          vreg[i] = *(const u16x8*)(vbase + off + (size_t)srow[i] * QKVW_ + scol[i] * 8);
        }
      }
    }
    f32x4 sacc[7] = {};
    #pragma unroll
    for (int ks = 0; ks < 3; ++ks) {
      bf16x8 af = *(const bf16x8*)&A_lds[(wid * 16 + l16) * AKS_ + ks * 32 + lq * 8];
      #pragma unroll
      for (int nt = 0; nt < 7; ++nt) {
        bf16x8 bf = *(const bf16x8*)&K_lds[(nt * 16 + l16) * AKS_ + ks * 32 + lq * 8];
        sacc[nt] = __builtin_amdgcn_mfma_f32_16x16x32_bf16(af, bf, sacc[nt], 0, 0, 0);
      }
    }
    float cmax[4] = {-1e30f, -1e30f, -1e30f, -1e30f};
    const int nb = c * 112 + l16;
    #pragma unroll
    for (int nt = 0; nt < 7; ++nt)
      #pragma unroll
      for (int r = 0; r < 4; ++r) {
        float lg = sacc[nt][r] * SCALE_ + bias_base[r][nb + nt * 16];
        sacc[nt][r] = lg;
        cmax[r] = fmaxf(cmax[r], lg);
      }
    #pragma unroll
    for (int off = 1; off < 16; off <<= 1)
      #pragma unroll
      for (int r = 0; r < 4; ++r)
        cmax[r] = fmaxf(cmax[r], __shfl_xor(cmax[r], off));
    float scl[4], rs[4];
    #pragma unroll
    for (int r = 0; r < 4; ++r) {
      float nm = fmaxf(m_r[r], cmax[r]);
      scl[r] = __expf(m_r[r] - nm);
      m_r[r] = nm;
      rs[r] = 0.f;
    }
    #pragma unroll
    for (int nt = 0; nt < 7; ++nt)
      #pragma unroll
      for (int r = 0; r < 4; ++r) {
        float p = __expf(sacc[nt][r] - m_r[r]);
        rs[r] += p;
        P_lds[wid][(lq * 4 + r) * VTS_ + nt * 16 + l16] = f2bf(p);
      }
    #pragma unroll
    for (int off = 1; off < 16; off <<= 1)
      #pragma unroll
      for (int r = 0; r < 4; ++r)
        rs[r] += __shfl_xor(rs[r], off);
    #pragma unroll
    for (int r = 0; r < 4; ++r) l_r[r] = l_r[r] * scl[r] + rs[r];
    #pragma unroll
    for (int nt = 0; nt < 5; ++nt)
      #pragma unroll
      for (int r = 0; r < 4; ++r) O[nt][r] *= scl[r];
    #pragma unroll
    for (int ks = 0; ks < 4; ++ks) {
      bf16x8 pf = *(const bf16x8*)&P_lds[wid][l16 * VTS_ + ks * 32 + lq * 8];
      #pragma unroll
      for (int nt = 0; nt < 5; ++nt) {
        bf16x8 vf = *(const bf16x8*)&Vt_lds[(nt * 16 + l16) * VTS_ + ks * 32 + lq * 8];
        O[nt] = __builtin_amdgcn_mfma_f32_16x16x32_bf16(pf, vf, O[nt], 0, 0, 0);
      }
    }
    __syncthreads();
    if (c < 6) {
      #pragma unroll
      for (int i = 0; i < 4; ++i) {
        if (sval[i]) {
          *(u16x8*)&K_lds[srow[i] * AKS_ + scol[i] * 8] = kreg[i];
          #pragma unroll
          for (int e = 0; e < 8; ++e)
            Vt_lds[(scol[i] * 8 + e) * VTS_ + srow[i]] = vreg[i][e];
        }
      }
      __syncthreads();
    }
  }
  float inv[4];
  #pragma unroll
  for (int r = 0; r < 4; ++r) inv[r] = 1.f / l_r[r];
  #pragma unroll
  for (int nt = 0; nt < 5; ++nt) {
    int d = nt * 16 + l16;
    if (d >= HD_) continue;
    #pragma unroll
    for (int r = 0; r < 4; ++r) {
      int a = wid * 16 + lq * 4 + r;
      if (a < AGENT_)
        agent_v[(((size_t)b * HEADS_ + h) * AGENT_ + a) * HD_ + d] = O[nt][r] * inv[r];
    }
  }
}

// ---------------- q attention ----------------
__global__ __launch_bounds__(256) void q_attn_kernel(
    const ushort_t* __restrict__ qkvb, const float* __restrict__ agent,
    const float* __restrict__ agent_v, const float* __restrict__ qbias,
    float* __restrict__ xf) {
  __shared__ float ag_t[HD_ * 52];
  __shared__ float av_t[HD_ * 52];
  const int tid = threadIdx.x;
  const int h = blockIdx.y, b = blockIdx.z;
  for (int t = tid; t < AGENT_ * HD_; t += 256) {
    int a = t / HD_, d = t % HD_;
    ag_t[d * 52 + a] = agent[((size_t)b * AGENT_ + a) * C_ + h * HD_ + d];
    av_t[d * 52 + a] = agent_v[(((size_t)b * HEADS_ + h) * AGENT_ + a) * HD_ + d];
  }
  __syncthreads();
  const int n = blockIdx.x * 256 + tid;
  if (n >= N_) return;
  const ushort_t* qp = qkvb + ((size_t)b * N_ + n) * QKVW_ + h * HD_;
  const float* qb = qbias + ((size_t)h * N_ + n) * AGENT_;
  float lg[AGENT_];
  #pragma unroll
  for (int a = 0; a < AGENT_; ++a) lg[a] = qb[a];
  for (int d = 0; d < HD_; ++d) {
    float qd = bf2f(qp[d]) * SCALE_;
    #pragma unroll
    for (int a = 0; a < AGENT_; ++a) lg[a] += qd * ag_t[d * 52 + a];
  }
  float mx = -1e30f;
  #pragma unroll
  for (int a = 0; a < AGENT_; ++a) mx = fmaxf(mx, lg[a]);
  float s = 0.f;
  #pragma unroll
  for (int a = 0; a < AGENT_; ++a) { lg[a] = __expf(lg[a] - mx); s += lg[a]; }
  float inv = 1.f / s;
  #pragma unroll
  for (int a = 0; a < AGENT_; ++a) lg[a] *= inv;
  float* op = xf + ((size_t)b * N_ + n) * C_ + h * HD_;
  for (int d = 0; d < HD_; ++d) {
    float acc = 0.f;
    #pragma unroll
    for (int a = 0; a < AGENT_; ++a) acc += lg[a] * av_t[d * 52 + a];
    op[d] = acc;
  }
}

// ---------------- depthwise conv + BN + ReLU (2ch/thread, XCD swizzle) ------
__global__ __launch_bounds__(288) void dwc_kernel(
    const ushort_t* __restrict__ qkvb, const float* __restrict__ w,
    const float* __restrict__ bias, const float* __restrict__ gamma,
    const float* __restrict__ beta, const float* __restrict__ mean,
    const float* __restrict__ var, float* __restrict__ xf) {
  int lin = blockIdx.x;
  const int bn = (lin & 7) * 3136 + (lin >> 3);   // 25088 = 8*3136, bijective
  const int b = bn / N_, n = bn % N_;
  const int y = n / W_, x = n % W_;
  const int c0 = threadIdx.x * 2;
  float a0 = 0.f, a1 = 0.f;
  #pragma unroll
  for (int ky = 0; ky < 3; ++ky) {
    int yy = y + ky - 1;
    if (yy < 0 || yy >= H_) continue;
    #pragma unroll
    for (int kx = 0; kx < 3; ++kx) {
      int xx = x + kx - 1;
      if (xx < 0 || xx >= W_) continue;
      unsigned v = *(const unsigned*)(qkvb + ((size_t)b * N_ + yy * W_ + xx) * QKVW_ + 2 * C_ + c0);
      a0 += w[c0 * 9 + ky * 3 + kx] * bf2f((ushort_t)(v & 0xffffu));
      a1 += w[(c0 + 1) * 9 + ky * 3 + kx] * bf2f((ushort_t)(v >> 16));
    }
  }
  float s0 = gamma[c0] * rsqrtf(var[c0] + 1e-5f);
  float s1 = gamma[c0 + 1] * rsqrtf(var[c0 + 1] + 1e-5f);
  float r0 = fmaxf((a0 + bias[c0] - mean[c0]) * s0 + beta[c0], 0.f);
  float r1 = fmaxf((a1 + bias[c0 + 1] - mean[c0 + 1]) * s1 + beta[c0 + 1], 0.f);
  float2* xp = (float2*)&xf[(size_t)bn * C_ + c0];
  float2 old = *xp;
  old.x += r0; old.y += r1;
  *xp = old;
}

extern "C" void kernel_launch(void* const* d_in, const int* in_sizes, int n_in,
                              void* d_out, int out_size, void* d_ws, size_t ws_size,
                              hipStream_t stream) {
  const float* x        = (const float*)d_in[0];
  const float* Wq       = (const float*)d_in[3];
  const float* Wkv      = (const float*)d_in[4];
  const float* an_bias  = (const float*)d_in[5];
  const float* na_bias  = (const float*)d_in[6];
  const float* ah_bias  = (const float*)d_in[7];
  const float* aw_bias  = (const float*)d_in[8];
  const float* ha_bias  = (const float*)d_in[9];
  const float* wa_bias  = (const float*)d_in[10];
  const float* dwc_w    = (const float*)d_in[11];
  const float* dwc_b    = (const float*)d_in[12];
  const float* bn_gamma = (const float*)d_in[13];
  const float* bn_beta  = (const float*)d_in[14];
  const float* bn_mean  = (const float*)d_in[15];
  const float* bn_var   = (const float*)d_in[16];
  const float* base_w   = (const float*)d_in[17];
  const float* spline_w = (const float*)d_in[18];
  const float* spline_s = (const float*)d_in[19];

  char* ws = (char*)d_ws;
  ushort_t* qkvb   = (ushort_t*)(ws + 0);            // 86,704,128 B
  ushort_t* xbt    = (ushort_t*)(ws + 86704128);     // 28,901,376 B
  ushort_t* wbt    = (ushort_t*)(ws + 115605504);    //  1,990,656 B
  ushort_t* bpackb = (ushort_t*)(ws + 117596160);    //  5,971,968 B
  float* agent     = (float*)(ws + 123568128);
  float* agent_v   = (float*)(ws + 127180800);
  float* abias     = (float*)(ws + 130793472);
  float* qbias     = (float*)(ws + 132022784);
  float* xf        = (float*)(ws + 133252096);
  float* out       = (float*)d_out;

  convert_x_kernel<<<dim3(2048), dim3(256), 0, stream>>>(x, xbt);
  pack_w_kernel<<<dim3(81), dim3(256), 0, stream>>>(Wq, Wkv, wbt);
  pack_b_kernel<<<dim3(C_), dim3(256), 0, stream>>>(base_w, spline_w, spline_s, bpackb);
  bias_kernel<<<dim3((HEADS_ * AGENT_ * N_ + 255) / 256), dim3(256), 0, stream>>>(
      an_bias, na_bias, ah_bias, aw_bias, ha_bias, wa_bias, abias, qbias);
  mfma_qkv_kernel<<<dim3(1764), dim3(512), 0, stream>>>(xbt, wbt, qkvb);
  agent_pool_kernel<<<dim3(B_ * AGENT_), dim3(C_), 0, stream>>>(qkvb, agent);
  agent_attn_mfma_kernel<<<dim3(B_ * HEADS_), dim3(256), 0, stream>>>(
      agent, qkvb, abias, agent_v);
  q_attn_kernel<<<dim3(4, HEADS_, B_), dim3(256), 0, stream>>>(
      qkvb, agent, agent_v, qbias, xf);
  dwc_kernel<<<dim3(M_), dim3(288), 0, stream>>>(
      qkvb, dwc_w, dwc_b, bn_gamma, bn_beta, bn_mean, bn_var, xf);
  kan_mfma_kernel<<<dim3(588), dim3(512), 0, stream>>>(xf, bpackb, out);
}

// Round 14
// 671.473 us; speedup vs baseline: 1.4940x; 1.4940x over previous
//
#include <hip/hip_runtime.h>
#include <hip/hip_bf16.h>
#include <math.h>

#define B_ 32
#define N_ 784
#define C_ 576
#define H_ 28
#define W_ 28
#define HEADS_ 8
#define HD_ 72
#define AGENT_ 49
#define M_ (B_ * N_)            // 25088
#define KTOT_ 5184              // 576 silu + 576*8 spline
#define QKVW_ 1728
#define SCALE_ 0.11785113019775793f

// BK=64 swizzled LDS: row stride 64 elems (128 B); 16B chunks XOR'd by row&7.
// Verified conflict-free (rounds 7-12: SQ_LDS_BANK_CONFLICT = 0).
#define SWZ64(row, chunk) (((row) << 6) + ((((chunk) ^ ((row) & 7))) << 3))

typedef unsigned short ushort_t;
typedef __attribute__((ext_vector_type(8))) unsigned short u16x8;
typedef __attribute__((ext_vector_type(8))) __bf16 bf16x8;
typedef __attribute__((ext_vector_type(4))) float f32x4;
typedef __attribute__((ext_vector_type(4))) unsigned u32x4;

__device__ __forceinline__ ushort_t f2bf(float f) {
  union { float f; unsigned u; } v; v.f = f;
  unsigned r = v.u + 0x7fffu + ((v.u >> 16) & 1u);
  return (ushort_t)(r >> 16);
}
__device__ __forceinline__ float bf2f(ushort_t u) {
  union { unsigned u; float f; } v; v.u = ((unsigned)u) << 16;
  return v.f;
}
__device__ __forceinline__ unsigned pack2(float lo, float hi) {
  __bf16 a = (__bf16)lo, b = (__bf16)hi;
  unsigned short ua = __builtin_bit_cast(unsigned short, a);
  unsigned short ub = __builtin_bit_cast(unsigned short, b);
  return (unsigned)ua | ((unsigned)ub << 16);
}

// ---------------- merged prep: bias | pack_b | pack_w | convert_x ----------
__device__ __forceinline__ float bilerp7(const float* __restrict__ Bsrc, int y, int x) {
  float sy = y * 0.25f - 0.375f;
  float sx = x * 0.25f - 0.375f;
  float fy0 = floorf(sy), fx0 = floorf(sx);
  int y0 = (int)fy0, x0 = (int)fx0;
  float fy = sy - fy0, fx = sx - fx0;
  int y0c = min(6, max(0, y0)), y1c = min(6, max(0, y0 + 1));
  int x0c = min(6, max(0, x0)), x1c = min(6, max(0, x0 + 1));
  float v00 = Bsrc[y0c * 7 + x0c], v01 = Bsrc[y0c * 7 + x1c];
  float v10 = Bsrc[y1c * 7 + x0c], v11 = Bsrc[y1c * 7 + x1c];
  return (1.f - fy) * ((1.f - fx) * v00 + fx * v01)
       + fy * ((1.f - fx) * v10 + fx * v11);
}

#define PREP_BIAS_   1201
#define PREP_PACKB_  (PREP_BIAS_ + 576)    // 1777
#define PREP_PACKW_  (PREP_PACKB_ + 512)   // 2289
#define PREP_TOTAL_  (PREP_PACKW_ + 1024)  // 3313

__global__ __launch_bounds__(256) void prep_kernel(
    const float* __restrict__ x, ushort_t* __restrict__ xbf,
    const float* __restrict__ Wq, const float* __restrict__ Wkv,
    ushort_t* __restrict__ wbf,
    const float* __restrict__ base_w, const float* __restrict__ spline_w,
    const float* __restrict__ spline_s, ushort_t* __restrict__ bpackb,
    const float* __restrict__ an_bias, const float* __restrict__ na_bias,
    const float* __restrict__ ah_bias, const float* __restrict__ aw_bias,
    const float* __restrict__ ha_bias, const float* __restrict__ wa_bias,
    float* __restrict__ abias, float* __restrict__ qbias) {
  const int blk = blockIdx.x, tid = threadIdx.x;
  if (blk < PREP_BIAS_) {
    int idx = blk * 256 + tid;
    if (idx >= HEADS_ * AGENT_ * N_) return;
    int n = idx % N_;
    int ha = idx / N_;
    int h = ha / AGENT_, a = ha % AGENT_;
    int y = n / W_, xx = n % W_;
    float pb1 = bilerp7(an_bias + (size_t)ha * 49, y, xx);
    float pb2 = ah_bias[ha * H_ + y] + aw_bias[ha * W_ + xx];
    abias[(size_t)ha * N_ + n] = pb1 + pb2;
    float ab1 = bilerp7(na_bias + (size_t)ha * 49, y, xx);
    float ab2 = ha_bias[(h * H_ + y) * AGENT_ + a] + wa_bias[(h * W_ + xx) * AGENT_ + a];
    qbias[((size_t)h * N_ + n) * AGENT_ + a] = ab1 + ab2;
  } else if (blk < PREP_PACKB_) {
    int o = blk - PREP_BIAS_;
    for (int j = tid; j < KTOT_; j += 256) {
      float v;
      if (j < C_) {
        v = base_w[(size_t)o * C_ + j];
      } else {
        int jj = j - C_;
        int i = jj >> 3, kk = jj & 7;
        v = spline_w[((size_t)o * C_ + i) * 8 + kk] * spline_s[(size_t)o * C_ + i];
      }
      bpackb[(size_t)o * KTOT_ + j] = f2bf(v);
    }
  } else if (blk < PREP_PACKW_) {
    int total = QKVW_ * C_;
    for (int i = (blk - PREP_PACKB_) * 256 + tid; i < total; i += 512 * 256) {
      int j = i / C_, k = i % C_;
      float v = (j < C_) ? Wq[(size_t)j * C_ + k] : Wkv[(size_t)(j - C_) * C_ + k];
      wbf[i] = f2bf(v);
    }
  } else {
    const int total8 = M_ * C_ / 8;
    for (int i = (blk - PREP_PACKW_) * 256 + tid; i < total8; i += 1024 * 256) {
      f32x4 a = *(const f32x4*)(x + i * 8);
      f32x4 b = *(const f32x4*)(x + i * 8 + 4);
      u16x8 o;
      o[0]=f2bf(a[0]); o[1]=f2bf(a[1]); o[2]=f2bf(a[2]); o[3]=f2bf(a[3]);
      o[4]=f2bf(b[0]); o[5]=f2bf(b[1]); o[6]=f2bf(b[2]); o[7]=f2bf(b[3]);
      *(u16x8*)(xbf + i * 8) = o;
    }
  }
}

// ---------------- MFMA GEMM: qkv (8 waves, BK=64, write/load-first order) ---
// grid: 1764 = 196 row-tiles x 9 col-tiles (col fastest); 1764 = 8*220+4
__global__ __launch_bounds__(512, 4) void mfma_qkv_kernel(
    const ushort_t* __restrict__ A, const ushort_t* __restrict__ Bt,
    ushort_t* __restrict__ out) {
  __shared__ ushort_t Asl[2][128 * 64];   // 32 KB
  __shared__ ushort_t Bsl[2][192 * 64];   // 48 KB
  const int tid = threadIdx.x;
  const int lane = tid & 63, wid = tid >> 6;
  const int wm = wid >> 2, wn = wid & 3;
  const int l16 = lane & 15, lq = lane >> 4;

  int lin = blockIdx.x;
  const int q = 220, r = 4;          // 1764 = 8*220+4
  int xcd = lin & 7;
  int wg = (xcd < r ? xcd * (q + 1) : r * (q + 1) + (xcd - r) * q) + (lin >> 3);
  const int m0 = (wg / 9) * 128, n0 = (wg % 9) * 192;

  const int srowi = tid >> 3;        // 0..63
  const int chk = tid & 7;           // 0..7

  const ushort_t* arow0 = A + (size_t)(m0 + srowi) * C_ + chk * 8;
  const ushort_t* arow1 = arow0 + (size_t)64 * C_;
  const ushort_t* brow0 = Bt + (size_t)(n0 + srowi) * C_ + chk * 8;
  const ushort_t* brow1 = brow0 + (size_t)64 * C_;
  const ushort_t* brow2 = brow0 + (size_t)128 * C_;

  const int aW0 = SWZ64(srowi, chk), aW1 = SWZ64(srowi + 64, chk);
  const int bW0 = SWZ64(srowi, chk), bW1 = SWZ64(srowi + 64, chk),
            bW2 = SWZ64(srowi + 128, chk);

  f32x4 acc[4][3] = {};
  u16x8 ar0, ar1, br0, br1, br2;

  // prologue: step0 load + write buf0, step1 load
  ar0 = *(const u16x8*)(arow0);
  ar1 = *(const u16x8*)(arow1);
  br0 = *(const u16x8*)(brow0);
  br1 = *(const u16x8*)(brow1);
  br2 = *(const u16x8*)(brow2);
  *(u16x8*)&Asl[0][aW0] = ar0;
  *(u16x8*)&Asl[0][aW1] = ar1;
  *(u16x8*)&Bsl[0][bW0] = br0;
  *(u16x8*)&Bsl[0][bW1] = br1;
  *(u16x8*)&Bsl[0][bW2] = br2;
  ar0 = *(const u16x8*)(arow0 + 64);
  ar1 = *(const u16x8*)(arow1 + 64);
  br0 = *(const u16x8*)(brow0 + 64);
  br1 = *(const u16x8*)(brow1 + 64);
  br2 = *(const u16x8*)(brow2 + 64);
  __syncthreads();

  const int NSTEP = C_ / 64;   // 9
  for (int s = 0; s < NSTEP; ++s) {
    const int cur = s & 1;
    if (s + 1 < NSTEP) {
      const int nxt = cur ^ 1;
      *(u16x8*)&Asl[nxt][aW0] = ar0;
      *(u16x8*)&Asl[nxt][aW1] = ar1;
      *(u16x8*)&Bsl[nxt][bW0] = br0;
      *(u16x8*)&Bsl[nxt][bW1] = br1;
      *(u16x8*)&Bsl[nxt][bW2] = br2;
      if (s + 2 < NSTEP) {
        const int kl = (s + 2) * 64;
        ar0 = *(const u16x8*)(arow0 + kl);
        ar1 = *(const u16x8*)(arow1 + kl);
        br0 = *(const u16x8*)(brow0 + kl);
        br1 = *(const u16x8*)(brow1 + kl);
        br2 = *(const u16x8*)(brow2 + kl);
      }
    }
    #pragma unroll
    for (int ks = 0; ks < 2; ++ks) {
      bf16x8 af[4], bfr[3];
      #pragma unroll
      for (int fm = 0; fm < 4; ++fm)
        af[fm] = *(const bf16x8*)&Asl[cur][SWZ64(wm * 64 + fm * 16 + l16, ks * 4 + lq)];
      #pragma unroll
      for (int fn = 0; fn < 3; ++fn)
        bfr[fn] = *(const bf16x8*)&Bsl[cur][SWZ64(wn * 48 + fn * 16 + l16, ks * 4 + lq)];
      #pragma unroll
      for (int fm = 0; fm < 4; ++fm)
        #pragma unroll
        for (int fn = 0; fn < 3; ++fn)
          acc[fm][fn] = __builtin_amdgcn_mfma_f32_16x16x32_bf16(
              af[fm], bfr[fn], acc[fm][fn], 0, 0, 0);
    }
    __syncthreads();
  }
  #pragma unroll
  for (int fm = 0; fm < 4; ++fm) {
    #pragma unroll
    for (int fn = 0; fn < 3; ++fn) {
      int col = n0 + wn * 48 + fn * 16 + l16;
      #pragma unroll
      for (int r2 = 0; r2 < 4; ++r2) {
        int row = m0 + wm * 64 + fm * 16 + lq * 4 + r2;
        out[(size_t)row * QKVW_ + col] = f2bf(acc[fm][fn][r2]);
      }
    }
  }
}

// ---------------- KAN A-operand generation (funnel-shift placement) --------
__device__ __forceinline__ u32x4 basesPack(float xv) {
  float s = __fmaf_rn(xv, 2.5f, 5.5f);
  float tf = floorf(s);
  int t = (int)tf;
  float u = s - tf;
  float u2 = u * u, u3 = u2 * u, um = 1.f - u;
  float p0 = u3 * (1.f / 6.f);
  float p1 = __fmaf_rn(u3, -0.5f, __fmaf_rn(u2, 0.5f, __fmaf_rn(u, 0.5f, 1.f / 6.f)));
  float p2 = __fmaf_rn(u3, 0.5f, __fmaf_rn(u2, -1.f, 2.f / 3.f));
  float p3 = um * um * um * (1.f / 6.f);
  unsigned lo = pack2(p3, p2);          // slot0=p3, slot1=p2
  unsigned hi = pack2(p1, p0);          // slot2=p1, slot3=p0
  unsigned long long packed = ((unsigned long long)hi << 32) | (unsigned long long)lo;
  int sh = t - 3;
  int ba = sh << 4;
  unsigned long long shl_lo = packed << (ba & 63);
  unsigned long long shr_sp = packed >> ((64 - ba) & 63);
  unsigned long long shl_hi = packed << ((ba - 64) & 63);
  unsigned long long shr_ng = packed >> ((-ba) & 63);
  unsigned long long Olo = (sh < 0) ? shr_ng : ((sh < 4) ? shl_lo : 0ull);
  unsigned long long Ohi = (sh <= 0) ? 0ull : ((sh < 4) ? shr_sp : shl_hi);
  if (t < 0 || t > 10) { Olo = 0ull; Ohi = 0ull; }
  u32x4 o;
  o[0] = (unsigned)Olo; o[1] = (unsigned)(Olo >> 32);
  o[2] = (unsigned)Ohi; o[3] = (unsigned)(Ohi >> 32);
  return o;
}

__device__ __forceinline__ u32x4 siluPack(const float* xv) {
  u32x4 o;
  #pragma unroll
  for (int e = 0; e < 4; ++e) {
    float v0 = xv[2 * e], v1 = xv[2 * e + 1];
    float s0 = v0 / (1.f + __expf(-v0));
    float s1 = v1 / (1.f + __expf(-v1));
    o[e] = pack2(s0, s1);
  }
  return o;
}

// ---------------- KAN MFMA GEMM (8 waves, BK=64, write/load-first order) ----
// grid: 588 = 196 row-tiles x 3 col-tiles (col fastest); 588 = 8*73+4
__global__ __launch_bounds__(512, 4) void kan_mfma_kernel(
    const float* __restrict__ xf, const ushort_t* __restrict__ Bt,
    float* __restrict__ out) {
  __shared__ ushort_t Asl[2][128 * 64];   // 32 KB
  __shared__ ushort_t Bsl[2][192 * 64];   // 48 KB
  const int tid = threadIdx.x;
  const int lane = tid & 63, wid = tid >> 6;
  const int wm = wid >> 2, wn = wid & 3;
  const int l16 = lane & 15, lq = lane >> 4;

  int lin = blockIdx.x;
  const int q = 73, r = 4;           // 588 = 8*73+4
  int xcd = lin & 7;
  int wg = (xcd < r ? xcd * (q + 1) : r * (q + 1) + (xcd - r) * q) + (lin >> 3);
  const int m0 = (wg / 3) * 128, n0 = (wg % 3) * 192;

  const int srowi = tid >> 3;        // 0..63
  const int chk = tid & 7;           // 0..7

  const float* xfr0 = xf + (size_t)(m0 + srowi) * C_;
  const float* xfr1 = xfr0 + (size_t)64 * C_;
  const ushort_t* brow0 = Bt + (size_t)(n0 + srowi) * KTOT_ + chk * 8;
  const ushort_t* brow1 = brow0 + (size_t)64 * KTOT_;
  const ushort_t* brow2 = brow0 + (size_t)128 * KTOT_;

  const int aW0 = SWZ64(srowi, chk), aW1 = SWZ64(srowi + 64, chk);
  const int bW0 = SWZ64(srowi, chk), bW1 = SWZ64(srowi + 64, chk),
            bW2 = SWZ64(srowi + 128, chk);

  f32x4 acc[4][3] = {};
  float xv0[8], xv1[8];
  u16x8 br0, br1, br2;

  // prologue: step0 load + gen + write buf0, step1 load
  {
    f32x4 a = *(const f32x4*)(xfr0 + chk * 8);
    f32x4 b = *(const f32x4*)(xfr0 + chk * 8 + 4);
    xv0[0]=a[0]; xv0[1]=a[1]; xv0[2]=a[2]; xv0[3]=a[3];
    xv0[4]=b[0]; xv0[5]=b[1]; xv0[6]=b[2]; xv0[7]=b[3];
    f32x4 c = *(const f32x4*)(xfr1 + chk * 8);
    f32x4 d = *(const f32x4*)(xfr1 + chk * 8 + 4);
    xv1[0]=c[0]; xv1[1]=c[1]; xv1[2]=c[2]; xv1[3]=c[3];
    xv1[4]=d[0]; xv1[5]=d[1]; xv1[6]=d[2]; xv1[7]=d[3];
  }
  br0 = *(const u16x8*)(brow0);
  br1 = *(const u16x8*)(brow1);
  br2 = *(const u16x8*)(brow2);
  *(u32x4*)&Asl[0][aW0] = siluPack(xv0);
  *(u32x4*)&Asl[0][aW1] = siluPack(xv1);
  *(u16x8*)&Bsl[0][bW0] = br0;
  *(u16x8*)&Bsl[0][bW1] = br1;
  *(u16x8*)&Bsl[0][bW2] = br2;
  {
    f32x4 a = *(const f32x4*)(xfr0 + 64 + chk * 8);
    f32x4 b = *(const f32x4*)(xfr0 + 64 + chk * 8 + 4);
    xv0[0]=a[0]; xv0[1]=a[1]; xv0[2]=a[2]; xv0[3]=a[3];
    xv0[4]=b[0]; xv0[5]=b[1]; xv0[6]=b[2]; xv0[7]=b[3];
    f32x4 c = *(const f32x4*)(xfr1 + 64 + chk * 8);
    f32x4 d = *(const f32x4*)(xfr1 + 64 + chk * 8 + 4);
    xv1[0]=c[0]; xv1[1]=c[1]; xv1[2]=c[2]; xv1[3]=c[3];
    xv1[4]=d[0]; xv1[5]=d[1]; xv1[6]=d[2]; xv1[7]=d[3];
  }
  br0 = *(const u16x8*)(brow0 + 64);
  br1 = *(const u16x8*)(brow1 + 64);
  br2 = *(const u16x8*)(brow2 + 64);
  __syncthreads();

  const int NSTEP = KTOT_ / 64;   // 81
  for (int s = 0; s < NSTEP; ++s) {
    const int cur = s & 1;
    if (s + 1 < NSTEP) {
      const int nxt = cur ^ 1;
      const int kg = (s + 1) * 64;
      u32x4 a0, a1;
      if (kg < C_) { a0 = siluPack(xv0); a1 = siluPack(xv1); }
      else         { a0 = basesPack(xv0[0]); a1 = basesPack(xv1[0]); }
      *(u32x4*)&Asl[nxt][aW0] = a0;
      *(u32x4*)&Asl[nxt][aW1] = a1;
      *(u16x8*)&Bsl[nxt][bW0] = br0;
      *(u16x8*)&Bsl[nxt][bW1] = br1;
      *(u16x8*)&Bsl[nxt][bW2] = br2;
      if (s + 2 < NSTEP) {
        const int kl = (s + 2) * 64;
        if (kl < C_) {
          f32x4 a = *(const f32x4*)(xfr0 + kl + chk * 8);
          f32x4 b = *(const f32x4*)(xfr0 + kl + chk * 8 + 4);
          xv0[0]=a[0]; xv0[1]=a[1]; xv0[2]=a[2]; xv0[3]=a[3];
          xv0[4]=b[0]; xv0[5]=b[1]; xv0[6]=b[2]; xv0[7]=b[3];
          f32x4 c = *(const f32x4*)(xfr1 + kl + chk * 8);
          f32x4 d = *(const f32x4*)(xfr1 + kl + chk * 8 + 4);
          xv1[0]=c[0]; xv1[1]=c[1]; xv1[2]=c[2]; xv1[3]=c[3];
          xv1[4]=d[0]; xv1[5]=d[1]; xv1[6]=d[2]; xv1[7]=d[3];
        } else {
          int i0 = ((kl - C_) >> 3) + chk;
          xv0[0] = xfr0[i0];
          xv1[0] = xfr1[i0];
        }
        br0 = *(const u16x8*)(brow0 + kl);
        br1 = *(const u16x8*)(brow1 + kl);
        br2 = *(const u16x8*)(brow2 + kl);
      }
    }
    #pragma unroll
    for (int ks = 0; ks < 2; ++ks) {
      bf16x8 af[4], bfr[3];
      #pragma unroll
      for (int fm = 0; fm < 4; ++fm)
        af[fm] = *(const bf16x8*)&Asl[cur][SWZ64(wm * 64 + fm * 16 + l16, ks * 4 + lq)];
      #pragma unroll
      for (int fn = 0; fn < 3; ++fn)
        bfr[fn] = *(const bf16x8*)&Bsl[cur][SWZ64(wn * 48 + fn * 16 + l16, ks * 4 + lq)];
      #pragma unroll
      for (int fm = 0; fm < 4; ++fm)
        #pragma unroll
        for (int fn = 0; fn < 3; ++fn)
          acc[fm][fn] = __builtin_amdgcn_mfma_f32_16x16x32_bf16(
              af[fm], bfr[fn], acc[fm][fn], 0, 0, 0);
    }
    __syncthreads();
  }
  #pragma unroll
  for (int fm = 0; fm < 4; ++fm) {
    #pragma unroll
    for (int fn = 0; fn < 3; ++fn) {
      int col = n0 + wn * 48 + fn * 16 + l16;
      #pragma unroll
      for (int r2 = 0; r2 < 4; ++r2) {
        int row = m0 + wm * 64 + fm * 16 + lq * 4 + r2;
        out[(size_t)row * C_ + col] = acc[fm][fn][r2];
      }
    }
  }
}

// ---------------- agent pooling ----------------
__global__ __launch_bounds__(576) void agent_pool_kernel(
    const ushort_t* __restrict__ qkvb, float* __restrict__ agent) {
  int ba = blockIdx.x;
  int b = ba / AGENT_, a = ba % AGENT_;
  int ay = a / 7, ax = a % 7;
  int ch = threadIdx.x;
  float s = 0.f;
  #pragma unroll
  for (int i2 = 0; i2 < 4; ++i2)
    #pragma unroll
    for (int i4 = 0; i4 < 4; ++i4)
      s += bf2f(qkvb[((size_t)b * N_ + (ay * 4 + i2) * W_ + (ax * 4 + i4)) * QKVW_ + ch]);
  agent[(size_t)ba * C_ + ch] = s * 0.0625f;
}

// ---------------- agent attention v3: MFMA flash, one block per (b,h) -------
#define AKS_ 104
#define VTS_ 136
__global__ __launch_bounds__(256) void agent_attn_mfma_kernel(
    const float* __restrict__ agent, const ushort_t* __restrict__ qkvb,
    const float* __restrict__ abias, float* __restrict__ agent_v) {
  __shared__ ushort_t A_lds[64 * AKS_];
  __shared__ ushort_t K_lds[112 * AKS_];
  __shared__ ushort_t Vt_lds[80 * VTS_];
  __shared__ ushort_t P_lds[4][16 * VTS_];
  const int tid = threadIdx.x;
  const int lane = tid & 63, wid = tid >> 6;
  const int l16 = lane & 15, lq = lane >> 4;
  const int b = blockIdx.x >> 3, h = blockIdx.x & 7;

  for (int i = tid; i < 64 * AKS_; i += 256) A_lds[i] = 0;
  for (int i = tid; i < 112 * 32; i += 256) {
    int r = i >> 5, cc = 72 + (i & 31);
    K_lds[r * AKS_ + cc] = 0;
  }
  for (int i = tid; i < 80 * VTS_; i += 256) Vt_lds[i] = 0;
  for (int i = tid; i < 4 * 16 * 24; i += 256) {
    int w = i / (16 * 24), rest = i % (16 * 24);
    int r = rest / 24, cc = 112 + rest % 24;
    P_lds[w][r * VTS_ + cc] = 0;
  }
  for (int i = tid; i < AGENT_ * HD_; i += 256) {
    int a = i / HD_, d = i % HD_;
    A_lds[a * AKS_ + d] = f2bf(agent[((size_t)b * AGENT_ + a) * C_ + h * HD_ + d]);
  }

  int srow[4], scol[4]; bool sval[4];
  #pragma unroll
  for (int i = 0; i < 4; ++i) {
    int idx = tid + i * 256;
    srow[i] = idx / 9; scol[i] = idx % 9;
    sval[i] = idx < 1008;
  }
  const ushort_t* kbase = qkvb + (size_t)b * N_ * QKVW_ + C_ + h * HD_;
  const ushort_t* vbase = qkvb + (size_t)b * N_ * QKVW_ + 2 * C_ + h * HD_;

  u16x8 kreg[4], vreg[4];
  #pragma unroll
  for (int i = 0; i < 4; ++i) {
    if (sval[i]) {
      kreg[i] = *(const u16x8*)(kbase + (size_t)srow[i] * QKVW_ + scol[i] * 8);
      vreg[i] = *(const u16x8*)(vbase + (size_t)srow[i] * QKVW_ + scol[i] * 8);
    }
  }
  #pragma unroll
  for (int i = 0; i < 4; ++i) {
    if (sval[i]) {
      *(u16x8*)&K_lds[srow[i] * AKS_ + scol[i] * 8] = kreg[i];
      #pragma unroll
      for (int e = 0; e < 8; ++e)
        Vt_lds[(scol[i] * 8 + e) * VTS_ + srow[i]] = vreg[i][e];
    }
  }
  __syncthreads();

  float m_r[4] = {-1e30f, -1e30f, -1e30f, -1e30f};
  float l_r[4] = {};
  f32x4 O[5] = {};
  const float* bias_base[4];
  #pragma unroll
  for (int r = 0; r < 4; ++r) {
    int a = wid * 16 + lq * 4 + r;
    a = min(a, AGENT_ - 1);
    bias_base[r] = abias + ((size_t)h * AGENT_ + a) * N_;
  }

  for (int c = 0; c < 7; ++c) {
    if (c < 6) {
      const size_t off = (size_t)(c + 1) * 112 * QKVW_;
      #pragma unroll
      for (int i = 0; i < 4; ++i) {
        if (sval[i]) {
          kreg[i] = *(const u16x8*)(kbase + off + (size_t)srow[i] * QKVW_ + scol[i] * 8);
          vreg[i] = *(const u16x8*)(vbase + off + (size_t)srow[i] * QKVW_ + scol[i] * 8);
        }
      }
    }
    f32x4 sacc[7] = {};
    #pragma unroll
    for (int ks = 0; ks < 3; ++ks) {
      bf16x8 af = *(const bf16x8*)&A_lds[(wid * 16 + l16) * AKS_ + ks * 32 + lq * 8];
      #pragma unroll
      for (int nt = 0; nt < 7; ++nt) {
        bf16x8 bf = *(const bf16x8*)&K_lds[(nt * 16 + l16) * AKS_ + ks * 32 + lq * 8];
        sacc[nt] = __builtin_amdgcn_mfma_f32_16x16x32_bf16(af, bf, sacc[nt], 0, 0, 0);
      }
    }
    float cmax[4] = {-1e30f, -1e30f, -1e30f, -1e30f};
    const int nb = c * 112 + l16;
    #pragma unroll
    for (int nt = 0; nt < 7; ++nt)
      #pragma unroll
      for (int r = 0; r < 4; ++r) {
        float lg = sacc[nt][r] * SCALE_ + bias_base[r][nb + nt * 16];
        sacc[nt][r] = lg;
        cmax[r] = fmaxf(cmax[r], lg);
      }
    #pragma unroll
    for (int off = 1; off < 16; off <<= 1)
      #pragma unroll
      for (int r = 0; r < 4; ++r)
        cmax[r] = fmaxf(cmax[r], __shfl_xor(cmax[r], off));
    float scl[4], rs[4];
    #pragma unroll
    for (int r = 0; r < 4; ++r) {
      float nm = fmaxf(m_r[r], cmax[r]);
      scl[r] = __expf(m_r[r] - nm);
      m_r[r] = nm;
      rs[r] = 0.f;
    }
    #pragma unroll
    for (int nt = 0; nt < 7; ++nt)
      #pragma unroll
      for (int r = 0; r < 4; ++r) {
        float p = __expf(sacc[nt][r] - m_r[r]);
        rs[r] += p;
        P_lds[wid][(lq * 4 + r) * VTS_ + nt * 16 + l16] = f2bf(p);
      }
    #pragma unroll
    for (int off = 1; off < 16; off <<= 1)
      #pragma unroll
      for (int r = 0; r < 4; ++r)
        rs[r] += __shfl_xor(rs[r], off);
    #pragma unroll
    for (int r = 0; r < 4; ++r) l_r[r] = l_r[r] * scl[r] + rs[r];
    #pragma unroll
    for (int nt = 0; nt < 5; ++nt)
      #pragma unroll
      for (int r = 0; r < 4; ++r) O[nt][r] *= scl[r];
    #pragma unroll
    for (int ks = 0; ks < 4; ++ks) {
      bf16x8 pf = *(const bf16x8*)&P_lds[wid][l16 * VTS_ + ks * 32 + lq * 8];
      #pragma unroll
      for (int nt = 0; nt < 5; ++nt) {
        bf16x8 vf = *(const bf16x8*)&Vt_lds[(nt * 16 + l16) * VTS_ + ks * 32 + lq * 8];
        O[nt] = __builtin_amdgcn_mfma_f32_16x16x32_bf16(pf, vf, O[nt], 0, 0, 0);
      }
    }
    __syncthreads();
    if (c < 6) {
      #pragma unroll
      for (int i = 0; i < 4; ++i) {
        if (sval[i]) {
          *(u16x8*)&K_lds[srow[i] * AKS_ + scol[i] * 8] = kreg[i];
          #pragma unroll
          for (int e = 0; e < 8; ++e)
            Vt_lds[(scol[i] * 8 + e) * VTS_ + srow[i]] = vreg[i][e];
        }
      }
      __syncthreads();
    }
  }
  float inv[4];
  #pragma unroll
  for (int r = 0; r < 4; ++r) inv[r] = 1.f / l_r[r];
  #pragma unroll
  for (int nt = 0; nt < 5; ++nt) {
    int d = nt * 16 + l16;
    if (d >= HD_) continue;
    #pragma unroll
    for (int r = 0; r < 4; ++r) {
      int a = wid * 16 + lq * 4 + r;
      if (a < AGENT_)
        agent_v[(((size_t)b * HEADS_ + h) * AGENT_ + a) * HD_ + d] = O[nt][r] * inv[r];
    }
  }
}

// ---------------- q attention (vectorized loads / stores) ----------------
__global__ __launch_bounds__(256) void q_attn_kernel(
    const ushort_t* __restrict__ qkvb, const float* __restrict__ agent,
    const float* __restrict__ agent_v, const float* __restrict__ qbias,
    float* __restrict__ xf) {
  __shared__ float ag_t[HD_ * 52];
  __shared__ float av_t[HD_ * 52];
  const int tid = threadIdx.x;
  const int h = blockIdx.y, b = blockIdx.z;
  for (int t = tid; t < AGENT_ * HD_; t += 256) {
    int a = t / HD_, d = t % HD_;
    ag_t[d * 52 + a] = agent[((size_t)b * AGENT_ + a) * C_ + h * HD_ + d];
    av_t[d * 52 + a] = agent_v[(((size_t)b * HEADS_ + h) * AGENT_ + a) * HD_ + d];
  }
  __syncthreads();
  const int n = blockIdx.x * 256 + tid;
  if (n >= N_) return;
  const ushort_t* qp = qkvb + ((size_t)b * N_ + n) * QKVW_ + h * HD_;
  const float* qb = qbias + ((size_t)h * N_ + n) * AGENT_;
  u16x8 qv[9];
  #pragma unroll
  for (int d8 = 0; d8 < 9; ++d8) qv[d8] = *(const u16x8*)(qp + d8 * 8);
  float lg[AGENT_];
  #pragma unroll
  for (int a = 0; a < AGENT_; ++a) lg[a] = qb[a];
  for (int d8 = 0; d8 < 9; ++d8) {
    #pragma unroll
    for (int e = 0; e < 8; ++e) {
      float qd = bf2f(qv[d8][e]) * SCALE_;
      #pragma unroll
      for (int a = 0; a < AGENT_; ++a) lg[a] += qd * ag_t[(d8 * 8 + e) * 52 + a];
    }
  }
  float mx = -1e30f;
  #pragma unroll
  for (int a = 0; a < AGENT_; ++a) mx = fmaxf(mx, lg[a]);
  float s = 0.f;
  #pragma unroll
  for (int a = 0; a < AGENT_; ++a) { lg[a] = __expf(lg[a] - mx); s += lg[a]; }
  float inv = 1.f / s;
  #pragma unroll
  for (int a = 0; a < AGENT_; ++a) lg[a] *= inv;
  float* op = xf + ((size_t)b * N_ + n) * C_ + h * HD_;
  for (int d4 = 0; d4 < HD_ / 4; ++d4) {
    f32x4 v;
    #pragma unroll
    for (int e = 0; e < 4; ++e) {
      float acc = 0.f;
      #pragma unroll
      for (int a = 0; a < AGENT_; ++a) acc += lg[a] * av_t[(d4 * 4 + e) * 52 + a];
      v[e] = acc;
    }
    *(f32x4*)(op + d4 * 4) = v;
  }
}

// ---------------- depthwise conv + BN + ReLU (2ch/thread, XCD swizzle) ------
__global__ __launch_bounds__(288) void dwc_kernel(
    const ushort_t* __restrict__ qkvb, const float* __restrict__ w,
    const float* __restrict__ bias, const float* __restrict__ gamma,
    const float* __restrict__ beta, const float* __restrict__ mean,
    const float* __restrict__ var, float* __restrict__ xf) {
  int lin = blockIdx.x;
  const int bn = (lin & 7) * 3136 + (lin >> 3);   // 25088 = 8*3136, bijective
  const int b = bn / N_, n = bn % N_;
  const int y = n / W_, x = n % W_;
  const int c0 = threadIdx.x * 2;
  float a0 = 0.f, a1 = 0.f;
  #pragma unroll
  for (int ky = 0; ky < 3; ++ky) {
    int yy = y + ky - 1;
    if (yy < 0 || yy >= H_) continue;
    #pragma unroll
    for (int kx = 0; kx < 3; ++kx) {
      int xx = x + kx - 1;
      if (xx < 0 || xx >= W_) continue;
      unsigned v = *(const unsigned*)(qkvb + ((size_t)b * N_ + yy * W_ + xx) * QKVW_ + 2 * C_ + c0);
      a0 += w[c0 * 9 + ky * 3 + kx] * bf2f((ushort_t)(v & 0xffffu));
      a1 += w[(c0 + 1) * 9 + ky * 3 + kx] * bf2f((ushort_t)(v >> 16));
    }
  }
  float s0 = gamma[c0] * rsqrtf(var[c0] + 1e-5f);
  float s1 = gamma[c0 + 1] * rsqrtf(var[c0 + 1] + 1e-5f);
  float r0 = fmaxf((a0 + bias[c0] - mean[c0]) * s0 + beta[c0], 0.f);
  float r1 = fmaxf((a1 + bias[c0 + 1] - mean[c0 + 1]) * s1 + beta[c0 + 1], 0.f);
  float2* xp = (float2*)&xf[(size_t)bn * C_ + c0];
  float2 old = *xp;
  old.x += r0; old.y += r1;
  *xp = old;
}

extern "C" void kernel_launch(void* const* d_in, const int* in_sizes, int n_in,
                              void* d_out, int out_size, void* d_ws, size_t ws_size,
                              hipStream_t stream) {
  const float* x        = (const float*)d_in[0];
  const float* Wq       = (const float*)d_in[3];
  const float* Wkv      = (const float*)d_in[4];
  const float* an_bias  = (const float*)d_in[5];
  const float* na_bias  = (const float*)d_in[6];
  const float* ah_bias  = (const float*)d_in[7];
  const float* aw_bias  = (const float*)d_in[8];
  const float* ha_bias  = (const float*)d_in[9];
  const float* wa_bias  = (const float*)d_in[10];
  const float* dwc_w    = (const float*)d_in[11];
  const float* dwc_b    = (const float*)d_in[12];
  const float* bn_gamma = (const float*)d_in[13];
  const float* bn_beta  = (const float*)d_in[14];
  const float* bn_mean  = (const float*)d_in[15];
  const float* bn_var   = (const float*)d_in[16];
  const float* base_w   = (const float*)d_in[17];
  const float* spline_w = (const float*)d_in[18];
  const float* spline_s = (const float*)d_in[19];

  char* ws = (char*)d_ws;
  ushort_t* qkvb   = (ushort_t*)(ws + 0);
  ushort_t* xbf    = (ushort_t*)(ws + 86704128);
  ushort_t* wbf    = (ushort_t*)(ws + 115605504);
  ushort_t* bpackb = (ushort_t*)(ws + 117596160);
  float* agent     = (float*)(ws + 123568128);
  float* agent_v   = (float*)(ws + 127180800);
  float* abias     = (float*)(ws + 130793472);
  float* qbias     = (float*)(ws + 132022784);
  float* xf        = (float*)(ws + 133252096);
  float* out       = (float*)d_out;

  prep_kernel<<<dim3(PREP_TOTAL_), dim3(256), 0, stream>>>(
      x, xbf, Wq, Wkv, wbf, base_w, spline_w, spline_s, bpackb,
      an_bias, na_bias, ah_bias, aw_bias, ha_bias, wa_bias, abias, qbias);
  mfma_qkv_kernel<<<dim3(1764), dim3(512), 0, stream>>>(xbf, wbf, qkvb);
  agent_pool_kernel<<<dim3(B_ * AGENT_), dim3(C_), 0, stream>>>(qkvb, agent);
  agent_attn_mfma_kernel<<<dim3(B_ * HEADS_), dim3(256), 0, stream>>>(
      agent, qkvb, abias, agent_v);
  q_attn_kernel<<<dim3(4, HEADS_, B_), dim3(256), 0, stream>>>(
      qkvb, agent, agent_v, qbias, xf);
  dwc_kernel<<<dim3(M_), dim3(288), 0, stream>>>(
      qkvb, dwc_w, dwc_b, bn_gamma, bn_beta, bn_mean, bn_var, xf);
  kan_mfma_kernel<<<dim3(588), dim3(512), 0, stream>>>(xf, bpackb, out);
}

// Round 15
// 615.560 us; speedup vs baseline: 1.6297x; 1.0908x over previous
//
#include <hip/hip_runtime.h>
#include <hip/hip_bf16.h>
#include <math.h>

#define B_ 32
#define N_ 784
#define C_ 576
#define H_ 28
#define W_ 28
#define HEADS_ 8
#define HD_ 72
#define AGENT_ 49
#define M_ (B_ * N_)            // 25088
#define KTOT_ 5184              // 576 silu + 576*8 spline
#define QKVW_ 1728
#define SCALE_ 0.11785113019775793f

// BK=64 swizzled LDS: row stride 64 elems (128 B); 16B chunks XOR'd by row&7.
// Verified conflict-free (rounds 7-14: SQ_LDS_BANK_CONFLICT = 0).
#define SWZ64(row, chunk) (((row) << 6) + ((((chunk) ^ ((row) & 7))) << 3))

typedef unsigned short ushort_t;
typedef __attribute__((ext_vector_type(8))) unsigned short u16x8;
typedef __attribute__((ext_vector_type(8))) __bf16 bf16x8;
typedef __attribute__((ext_vector_type(4))) float f32x4;
typedef __attribute__((ext_vector_type(4))) unsigned u32x4;

__device__ __forceinline__ ushort_t f2bf(float f) {
  union { float f; unsigned u; } v; v.f = f;
  unsigned r = v.u + 0x7fffu + ((v.u >> 16) & 1u);
  return (ushort_t)(r >> 16);
}
__device__ __forceinline__ float bf2f(ushort_t u) {
  union { unsigned u; float f; } v; v.u = ((unsigned)u) << 16;
  return v.f;
}
__device__ __forceinline__ unsigned pack2(float lo, float hi) {
  __bf16 a = (__bf16)lo, b = (__bf16)hi;
  unsigned short ua = __builtin_bit_cast(unsigned short, a);
  unsigned short ub = __builtin_bit_cast(unsigned short, b);
  return (unsigned)ua | ((unsigned)ub << 16);
}

// ---------------- merged prep: bias | pack_b | pack_w | convert_x ----------
__device__ __forceinline__ float bilerp7(const float* __restrict__ Bsrc, int y, int x) {
  float sy = y * 0.25f - 0.375f;
  float sx = x * 0.25f - 0.375f;
  float fy0 = floorf(sy), fx0 = floorf(sx);
  int y0 = (int)fy0, x0 = (int)fx0;
  float fy = sy - fy0, fx = sx - fx0;
  int y0c = min(6, max(0, y0)), y1c = min(6, max(0, y0 + 1));
  int x0c = min(6, max(0, x0)), x1c = min(6, max(0, x0 + 1));
  float v00 = Bsrc[y0c * 7 + x0c], v01 = Bsrc[y0c * 7 + x1c];
  float v10 = Bsrc[y1c * 7 + x0c], v11 = Bsrc[y1c * 7 + x1c];
  return (1.f - fy) * ((1.f - fx) * v00 + fx * v01)
       + fy * ((1.f - fx) * v10 + fx * v11);
}

#define PREP_BIAS_   1201
#define PREP_PACKB_  (PREP_BIAS_ + 576)    // 1777
#define PREP_PACKW_  (PREP_PACKB_ + 512)   // 2289
#define PREP_TOTAL_  (PREP_PACKW_ + 1024)  // 3313

__global__ __launch_bounds__(256) void prep_kernel(
    const float* __restrict__ x, ushort_t* __restrict__ xbf,
    const float* __restrict__ Wq, const float* __restrict__ Wkv,
    ushort_t* __restrict__ wbf,
    const float* __restrict__ base_w, const float* __restrict__ spline_w,
    const float* __restrict__ spline_s, ushort_t* __restrict__ bpackb,
    const float* __restrict__ an_bias, const float* __restrict__ na_bias,
    const float* __restrict__ ah_bias, const float* __restrict__ aw_bias,
    const float* __restrict__ ha_bias, const float* __restrict__ wa_bias,
    float* __restrict__ abias, float* __restrict__ qbias) {
  const int blk = blockIdx.x, tid = threadIdx.x;
  if (blk < PREP_BIAS_) {
    int idx = blk * 256 + tid;
    if (idx >= HEADS_ * AGENT_ * N_) return;
    int n = idx % N_;
    int ha = idx / N_;
    int h = ha / AGENT_, a = ha % AGENT_;
    int y = n / W_, xx = n % W_;
    float pb1 = bilerp7(an_bias + (size_t)ha * 49, y, xx);
    float pb2 = ah_bias[ha * H_ + y] + aw_bias[ha * W_ + xx];
    abias[(size_t)ha * N_ + n] = pb1 + pb2;
    float ab1 = bilerp7(na_bias + (size_t)ha * 49, y, xx);
    float ab2 = ha_bias[(h * H_ + y) * AGENT_ + a] + wa_bias[(h * W_ + xx) * AGENT_ + a];
    qbias[((size_t)h * N_ + n) * AGENT_ + a] = ab1 + ab2;
  } else if (blk < PREP_PACKB_) {
    int o = blk - PREP_BIAS_;
    for (int j = tid; j < KTOT_; j += 256) {
      float v;
      if (j < C_) {
        v = base_w[(size_t)o * C_ + j];
      } else {
        int jj = j - C_;
        int i = jj >> 3, kk = jj & 7;
        v = spline_w[((size_t)o * C_ + i) * 8 + kk] * spline_s[(size_t)o * C_ + i];
      }
      bpackb[(size_t)o * KTOT_ + j] = f2bf(v);
    }
  } else if (blk < PREP_PACKW_) {
    int total = QKVW_ * C_;
    for (int i = (blk - PREP_PACKB_) * 256 + tid; i < total; i += 512 * 256) {
      int j = i / C_, k = i % C_;
      float v = (j < C_) ? Wq[(size_t)j * C_ + k] : Wkv[(size_t)(j - C_) * C_ + k];
      wbf[i] = f2bf(v);
    }
  } else {
    const int total8 = M_ * C_ / 8;
    for (int i = (blk - PREP_PACKW_) * 256 + tid; i < total8; i += 1024 * 256) {
      f32x4 a = *(const f32x4*)(x + i * 8);
      f32x4 b = *(const f32x4*)(x + i * 8 + 4);
      u16x8 o;
      o[0]=f2bf(a[0]); o[1]=f2bf(a[1]); o[2]=f2bf(a[2]); o[3]=f2bf(a[3]);
      o[4]=f2bf(b[0]); o[5]=f2bf(b[1]); o[6]=f2bf(b[2]); o[7]=f2bf(b[3]);
      *(u16x8*)(xbf + i * 8) = o;
    }
  }
}

// ---------------- MFMA GEMM: qkv (8 waves, BK=64, write/load-first order) ---
// grid: 1764 = 196 row-tiles x 9 col-tiles (col fastest); 1764 = 8*220+4
__global__ __launch_bounds__(512, 4) void mfma_qkv_kernel(
    const ushort_t* __restrict__ A, const ushort_t* __restrict__ Bt,
    ushort_t* __restrict__ out) {
  __shared__ ushort_t Asl[2][128 * 64];   // 32 KB
  __shared__ ushort_t Bsl[2][192 * 64];   // 48 KB
  const int tid = threadIdx.x;
  const int lane = tid & 63, wid = tid >> 6;
  const int wm = wid >> 2, wn = wid & 3;
  const int l16 = lane & 15, lq = lane >> 4;

  int lin = blockIdx.x;
  const int q = 220, r = 4;          // 1764 = 8*220+4
  int xcd = lin & 7;
  int wg = (xcd < r ? xcd * (q + 1) : r * (q + 1) + (xcd - r) * q) + (lin >> 3);
  const int m0 = (wg / 9) * 128, n0 = (wg % 9) * 192;

  const int srowi = tid >> 3;        // 0..63
  const int chk = tid & 7;           // 0..7

  const ushort_t* arow0 = A + (size_t)(m0 + srowi) * C_ + chk * 8;
  const ushort_t* arow1 = arow0 + (size_t)64 * C_;
  const ushort_t* brow0 = Bt + (size_t)(n0 + srowi) * C_ + chk * 8;
  const ushort_t* brow1 = brow0 + (size_t)64 * C_;
  const ushort_t* brow2 = brow0 + (size_t)128 * C_;

  const int aW0 = SWZ64(srowi, chk), aW1 = SWZ64(srowi + 64, chk);
  const int bW0 = SWZ64(srowi, chk), bW1 = SWZ64(srowi + 64, chk),
            bW2 = SWZ64(srowi + 128, chk);

  f32x4 acc[4][3] = {};
  u16x8 ar0, ar1, br0, br1, br2;

  // prologue: step0 load + write buf0, step1 load
  ar0 = *(const u16x8*)(arow0);
  ar1 = *(const u16x8*)(arow1);
  br0 = *(const u16x8*)(brow0);
  br1 = *(const u16x8*)(brow1);
  br2 = *(const u16x8*)(brow2);
  *(u16x8*)&Asl[0][aW0] = ar0;
  *(u16x8*)&Asl[0][aW1] = ar1;
  *(u16x8*)&Bsl[0][bW0] = br0;
  *(u16x8*)&Bsl[0][bW1] = br1;
  *(u16x8*)&Bsl[0][bW2] = br2;
  ar0 = *(const u16x8*)(arow0 + 64);
  ar1 = *(const u16x8*)(arow1 + 64);
  br0 = *(const u16x8*)(brow0 + 64);
  br1 = *(const u16x8*)(brow1 + 64);
  br2 = *(const u16x8*)(brow2 + 64);
  __syncthreads();

  const int NSTEP = C_ / 64;   // 9
  for (int s = 0; s < NSTEP; ++s) {
    const int cur = s & 1;
    if (s + 1 < NSTEP) {
      const int nxt = cur ^ 1;
      *(u16x8*)&Asl[nxt][aW0] = ar0;
      *(u16x8*)&Asl[nxt][aW1] = ar1;
      *(u16x8*)&Bsl[nxt][bW0] = br0;
      *(u16x8*)&Bsl[nxt][bW1] = br1;
      *(u16x8*)&Bsl[nxt][bW2] = br2;
      if (s + 2 < NSTEP) {
        const int kl = (s + 2) * 64;
        ar0 = *(const u16x8*)(arow0 + kl);
        ar1 = *(const u16x8*)(arow1 + kl);
        br0 = *(const u16x8*)(brow0 + kl);
        br1 = *(const u16x8*)(brow1 + kl);
        br2 = *(const u16x8*)(brow2 + kl);
      }
    }
    #pragma unroll
    for (int ks = 0; ks < 2; ++ks) {
      bf16x8 af[4], bfr[3];
      #pragma unroll
      for (int fm = 0; fm < 4; ++fm)
        af[fm] = *(const bf16x8*)&Asl[cur][SWZ64(wm * 64 + fm * 16 + l16, ks * 4 + lq)];
      #pragma unroll
      for (int fn = 0; fn < 3; ++fn)
        bfr[fn] = *(const bf16x8*)&Bsl[cur][SWZ64(wn * 48 + fn * 16 + l16, ks * 4 + lq)];
      #pragma unroll
      for (int fm = 0; fm < 4; ++fm)
        #pragma unroll
        for (int fn = 0; fn < 3; ++fn)
          acc[fm][fn] = __builtin_amdgcn_mfma_f32_16x16x32_bf16(
              af[fm], bfr[fn], acc[fm][fn], 0, 0, 0);
    }
    __syncthreads();
  }
  #pragma unroll
  for (int fm = 0; fm < 4; ++fm) {
    #pragma unroll
    for (int fn = 0; fn < 3; ++fn) {
      int col = n0 + wn * 48 + fn * 16 + l16;
      #pragma unroll
      for (int r2 = 0; r2 < 4; ++r2) {
        int row = m0 + wm * 64 + fm * 16 + lq * 4 + r2;
        out[(size_t)row * QKVW_ + col] = f2bf(acc[fm][fn][r2]);
      }
    }
  }
}

// ---------------- KAN A-operand generation (funnel-shift placement) --------
__device__ __forceinline__ u32x4 basesPack(float xv) {
  float s = __fmaf_rn(xv, 2.5f, 5.5f);
  float tf = floorf(s);
  int t = (int)tf;
  float u = s - tf;
  float u2 = u * u, u3 = u2 * u, um = 1.f - u;
  float p0 = u3 * (1.f / 6.f);
  float p1 = __fmaf_rn(u3, -0.5f, __fmaf_rn(u2, 0.5f, __fmaf_rn(u, 0.5f, 1.f / 6.f)));
  float p2 = __fmaf_rn(u3, 0.5f, __fmaf_rn(u2, -1.f, 2.f / 3.f));
  float p3 = um * um * um * (1.f / 6.f);
  unsigned lo = pack2(p3, p2);          // slot0=p3, slot1=p2
  unsigned hi = pack2(p1, p0);          // slot2=p1, slot3=p0
  unsigned long long packed = ((unsigned long long)hi << 32) | (unsigned long long)lo;
  int sh = t - 3;
  int ba = sh << 4;
  unsigned long long shl_lo = packed << (ba & 63);
  unsigned long long shr_sp = packed >> ((64 - ba) & 63);
  unsigned long long shl_hi = packed << ((ba - 64) & 63);
  unsigned long long shr_ng = packed >> ((-ba) & 63);
  unsigned long long Olo = (sh < 0) ? shr_ng : ((sh < 4) ? shl_lo : 0ull);
  unsigned long long Ohi = (sh <= 0) ? 0ull : ((sh < 4) ? shr_sp : shl_hi);
  if (t < 0 || t > 10) { Olo = 0ull; Ohi = 0ull; }
  u32x4 o;
  o[0] = (unsigned)Olo; o[1] = (unsigned)(Olo >> 32);
  o[2] = (unsigned)Ohi; o[3] = (unsigned)(Ohi >> 32);
  return o;
}

__device__ __forceinline__ u32x4 siluPack(const float* xv) {
  u32x4 o;
  #pragma unroll
  for (int e = 0; e < 4; ++e) {
    float v0 = xv[2 * e], v1 = xv[2 * e + 1];
    float s0 = v0 / (1.f + __expf(-v0));
    float s1 = v1 / (1.f + __expf(-v1));
    o[e] = pack2(s0, s1);
  }
  return o;
}

// ---------------- KAN MFMA GEMM (8 waves, BK=64, write/load-first order) ----
// grid: 588 = 196 row-tiles x 3 col-tiles (col fastest); 588 = 8*73+4
__global__ __launch_bounds__(512, 4) void kan_mfma_kernel(
    const float* __restrict__ xf, const ushort_t* __restrict__ Bt,
    float* __restrict__ out) {
  __shared__ ushort_t Asl[2][128 * 64];   // 32 KB
  __shared__ ushort_t Bsl[2][192 * 64];   // 48 KB
  const int tid = threadIdx.x;
  const int lane = tid & 63, wid = tid >> 6;
  const int wm = wid >> 2, wn = wid & 3;
  const int l16 = lane & 15, lq = lane >> 4;

  int lin = blockIdx.x;
  const int q = 73, r = 4;           // 588 = 8*73+4
  int xcd = lin & 7;
  int wg = (xcd < r ? xcd * (q + 1) : r * (q + 1) + (xcd - r) * q) + (lin >> 3);
  const int m0 = (wg / 3) * 128, n0 = (wg % 3) * 192;

  const int srowi = tid >> 3;        // 0..63
  const int chk = tid & 7;           // 0..7

  const float* xfr0 = xf + (size_t)(m0 + srowi) * C_;
  const float* xfr1 = xfr0 + (size_t)64 * C_;
  const ushort_t* brow0 = Bt + (size_t)(n0 + srowi) * KTOT_ + chk * 8;
  const ushort_t* brow1 = brow0 + (size_t)64 * KTOT_;
  const ushort_t* brow2 = brow0 + (size_t)128 * KTOT_;

  const int aW0 = SWZ64(srowi, chk), aW1 = SWZ64(srowi + 64, chk);
  const int bW0 = SWZ64(srowi, chk), bW1 = SWZ64(srowi + 64, chk),
            bW2 = SWZ64(srowi + 128, chk);

  f32x4 acc[4][3] = {};
  float xv0[8], xv1[8];
  u16x8 br0, br1, br2;

  // prologue: step0 load + gen + write buf0, step1 load
  {
    f32x4 a = *(const f32x4*)(xfr0 + chk * 8);
    f32x4 b = *(const f32x4*)(xfr0 + chk * 8 + 4);
    xv0[0]=a[0]; xv0[1]=a[1]; xv0[2]=a[2]; xv0[3]=a[3];
    xv0[4]=b[0]; xv0[5]=b[1]; xv0[6]=b[2]; xv0[7]=b[3];
    f32x4 c = *(const f32x4*)(xfr1 + chk * 8);
    f32x4 d = *(const f32x4*)(xfr1 + chk * 8 + 4);
    xv1[0]=c[0]; xv1[1]=c[1]; xv1[2]=c[2]; xv1[3]=c[3];
    xv1[4]=d[0]; xv1[5]=d[1]; xv1[6]=d[2]; xv1[7]=d[3];
  }
  br0 = *(const u16x8*)(brow0);
  br1 = *(const u16x8*)(brow1);
  br2 = *(const u16x8*)(brow2);
  *(u32x4*)&Asl[0][aW0] = siluPack(xv0);
  *(u32x4*)&Asl[0][aW1] = siluPack(xv1);
  *(u16x8*)&Bsl[0][bW0] = br0;
  *(u16x8*)&Bsl[0][bW1] = br1;
  *(u16x8*)&Bsl[0][bW2] = br2;
  {
    f32x4 a = *(const f32x4*)(xfr0 + 64 + chk * 8);
    f32x4 b = *(const f32x4*)(xfr0 + 64 + chk * 8 + 4);
    xv0[0]=a[0]; xv0[1]=a[1]; xv0[2]=a[2]; xv0[3]=a[3];
    xv0[4]=b[0]; xv0[5]=b[1]; xv0[6]=b[2]; xv0[7]=b[3];
    f32x4 c = *(const f32x4*)(xfr1 + 64 + chk * 8);
    f32x4 d = *(const f32x4*)(xfr1 + 64 + chk * 8 + 4);
    xv1[0]=c[0]; xv1[1]=c[1]; xv1[2]=c[2]; xv1[3]=c[3];
    xv1[4]=d[0]; xv1[5]=d[1]; xv1[6]=d[2]; xv1[7]=d[3];
  }
  br0 = *(const u16x8*)(brow0 + 64);
  br1 = *(const u16x8*)(brow1 + 64);
  br2 = *(const u16x8*)(brow2 + 64);
  __syncthreads();

  const int NSTEP = KTOT_ / 64;   // 81
  for (int s = 0; s < NSTEP; ++s) {
    const int cur = s & 1;
    if (s + 1 < NSTEP) {
      const int nxt = cur ^ 1;
      const int kg = (s + 1) * 64;
      u32x4 a0, a1;
      if (kg < C_) { a0 = siluPack(xv0); a1 = siluPack(xv1); }
      else         { a0 = basesPack(xv0[0]); a1 = basesPack(xv1[0]); }
      *(u32x4*)&Asl[nxt][aW0] = a0;
      *(u32x4*)&Asl[nxt][aW1] = a1;
      *(u16x8*)&Bsl[nxt][bW0] = br0;
      *(u16x8*)&Bsl[nxt][bW1] = br1;
      *(u16x8*)&Bsl[nxt][bW2] = br2;
      if (s + 2 < NSTEP) {
        const int kl = (s + 2) * 64;
        if (kl < C_) {
          f32x4 a = *(const f32x4*)(xfr0 + kl + chk * 8);
          f32x4 b = *(const f32x4*)(xfr0 + kl + chk * 8 + 4);
          xv0[0]=a[0]; xv0[1]=a[1]; xv0[2]=a[2]; xv0[3]=a[3];
          xv0[4]=b[0]; xv0[5]=b[1]; xv0[6]=b[2]; xv0[7]=b[3];
          f32x4 c = *(const f32x4*)(xfr1 + kl + chk * 8);
          f32x4 d = *(const f32x4*)(xfr1 + kl + chk * 8 + 4);
          xv1[0]=c[0]; xv1[1]=c[1]; xv1[2]=c[2]; xv1[3]=c[3];
          xv1[4]=d[0]; xv1[5]=d[1]; xv1[6]=d[2]; xv1[7]=d[3];
        } else {
          int i0 = ((kl - C_) >> 3) + chk;
          xv0[0] = xfr0[i0];
          xv1[0] = xfr1[i0];
        }
        br0 = *(const u16x8*)(brow0 + kl);
        br1 = *(const u16x8*)(brow1 + kl);
        br2 = *(const u16x8*)(brow2 + kl);
      }
    }
    #pragma unroll
    for (int ks = 0; ks < 2; ++ks) {
      bf16x8 af[4], bfr[3];
      #pragma unroll
      for (int fm = 0; fm < 4; ++fm)
        af[fm] = *(const bf16x8*)&Asl[cur][SWZ64(wm * 64 + fm * 16 + l16, ks * 4 + lq)];
      #pragma unroll
      for (int fn = 0; fn < 3; ++fn)
        bfr[fn] = *(const bf16x8*)&Bsl[cur][SWZ64(wn * 48 + fn * 16 + l16, ks * 4 + lq)];
      #pragma unroll
      for (int fm = 0; fm < 4; ++fm)
        #pragma unroll
        for (int fn = 0; fn < 3; ++fn)
          acc[fm][fn] = __builtin_amdgcn_mfma_f32_16x16x32_bf16(
              af[fm], bfr[fn], acc[fm][fn], 0, 0, 0);
    }
    __syncthreads();
  }
  #pragma unroll
  for (int fm = 0; fm < 4; ++fm) {
    #pragma unroll
    for (int fn = 0; fn < 3; ++fn) {
      int col = n0 + wn * 48 + fn * 16 + l16;
      #pragma unroll
      for (int r2 = 0; r2 < 4; ++r2) {
        int row = m0 + wm * 64 + fm * 16 + lq * 4 + r2;
        out[(size_t)row * C_ + col] = acc[fm][fn][r2];
      }
    }
  }
}

// ---------------- agent pooling ----------------
__global__ __launch_bounds__(576) void agent_pool_kernel(
    const ushort_t* __restrict__ qkvb, float* __restrict__ agent) {
  int ba = blockIdx.x;
  int b = ba / AGENT_, a = ba % AGENT_;
  int ay = a / 7, ax = a % 7;
  int ch = threadIdx.x;
  float s = 0.f;
  #pragma unroll
  for (int i2 = 0; i2 < 4; ++i2)
    #pragma unroll
    for (int i4 = 0; i4 < 4; ++i4)
      s += bf2f(qkvb[((size_t)b * N_ + (ay * 4 + i2) * W_ + (ax * 4 + i4)) * QKVW_ + ch]);
  agent[(size_t)ba * C_ + ch] = s * 0.0625f;
}

// ---------------- agent attention v3: MFMA flash, one block per (b,h) -------
#define AKS_ 104
#define VTS_ 136
__global__ __launch_bounds__(256) void agent_attn_mfma_kernel(
    const float* __restrict__ agent, const ushort_t* __restrict__ qkvb,
    const float* __restrict__ abias, float* __restrict__ agent_v) {
  __shared__ ushort_t A_lds[64 * AKS_];
  __shared__ ushort_t K_lds[112 * AKS_];
  __shared__ ushort_t Vt_lds[80 * VTS_];
  __shared__ ushort_t P_lds[4][16 * VTS_];
  const int tid = threadIdx.x;
  const int lane = tid & 63, wid = tid >> 6;
  const int l16 = lane & 15, lq = lane >> 4;
  const int b = blockIdx.x >> 3, h = blockIdx.x & 7;

  for (int i = tid; i < 64 * AKS_; i += 256) A_lds[i] = 0;
  for (int i = tid; i < 112 * 32; i += 256) {
    int r = i >> 5, cc = 72 + (i & 31);
    K_lds[r * AKS_ + cc] = 0;
  }
  for (int i = tid; i < 80 * VTS_; i += 256) Vt_lds[i] = 0;
  for (int i = tid; i < 4 * 16 * 24; i += 256) {
    int w = i / (16 * 24), rest = i % (16 * 24);
    int r = rest / 24, cc = 112 + rest % 24;
    P_lds[w][r * VTS_ + cc] = 0;
  }
  for (int i = tid; i < AGENT_ * HD_; i += 256) {
    int a = i / HD_, d = i % HD_;
    A_lds[a * AKS_ + d] = f2bf(agent[((size_t)b * AGENT_ + a) * C_ + h * HD_ + d]);
  }

  int srow[4], scol[4]; bool sval[4];
  #pragma unroll
  for (int i = 0; i < 4; ++i) {
    int idx = tid + i * 256;
    srow[i] = idx / 9; scol[i] = idx % 9;
    sval[i] = idx < 1008;
  }
  const ushort_t* kbase = qkvb + (size_t)b * N_ * QKVW_ + C_ + h * HD_;
  const ushort_t* vbase = qkvb + (size_t)b * N_ * QKVW_ + 2 * C_ + h * HD_;

  u16x8 kreg[4], vreg[4];
  #pragma unroll
  for (int i = 0; i < 4; ++i) {
    if (sval[i]) {
      kreg[i] = *(const u16x8*)(kbase + (size_t)srow[i] * QKVW_ + scol[i] * 8);
      vreg[i] = *(const u16x8*)(vbase + (size_t)srow[i] * QKVW_ + scol[i] * 8);
    }
  }
  #pragma unroll
  for (int i = 0; i < 4; ++i) {
    if (sval[i]) {
      *(u16x8*)&K_lds[srow[i] * AKS_ + scol[i] * 8] = kreg[i];
      #pragma unroll
      for (int e = 0; e < 8; ++e)
        Vt_lds[(scol[i] * 8 + e) * VTS_ + srow[i]] = vreg[i][e];
    }
  }
  __syncthreads();

  float m_r[4] = {-1e30f, -1e30f, -1e30f, -1e30f};
  float l_r[4] = {};
  f32x4 O[5] = {};
  const float* bias_base[4];
  #pragma unroll
  for (int r = 0; r < 4; ++r) {
    int a = wid * 16 + lq * 4 + r;
    a = min(a, AGENT_ - 1);
    bias_base[r] = abias + ((size_t)h * AGENT_ + a) * N_;
  }

  for (int c = 0; c < 7; ++c) {
    if (c < 6) {
      const size_t off = (size_t)(c + 1) * 112 * QKVW_;
      #pragma unroll
      for (int i = 0; i < 4; ++i) {
        if (sval[i]) {
          kreg[i] = *(const u16x8*)(kbase + off + (size_t)srow[i] * QKVW_ + scol[i] * 8);
          vreg[i] = *(const u16x8*)(vbase + off + (size_t)srow[i] * QKVW_ + scol[i] * 8);
        }
      }
    }
    f32x4 sacc[7] = {};
    #pragma unroll
    for (int ks = 0; ks < 3; ++ks) {
      bf16x8 af = *(const bf16x8*)&A_lds[(wid * 16 + l16) * AKS_ + ks * 32 + lq * 8];
      #pragma unroll
      for (int nt = 0; nt < 7; ++nt) {
        bf16x8 bf = *(const bf16x8*)&K_lds[(nt * 16 + l16) * AKS_ + ks * 32 + lq * 8];
        sacc[nt] = __builtin_amdgcn_mfma_f32_16x16x32_bf16(af, bf, sacc[nt], 0, 0, 0);
      }
    }
    float cmax[4] = {-1e30f, -1e30f, -1e30f, -1e30f};
    const int nb = c * 112 + l16;
    #pragma unroll
    for (int nt = 0; nt < 7; ++nt)
      #pragma unroll
      for (int r = 0; r < 4; ++r) {
        float lg = sacc[nt][r] * SCALE_ + bias_base[r][nb + nt * 16];
        sacc[nt][r] = lg;
        cmax[r] = fmaxf(cmax[r], lg);
      }
    #pragma unroll
    for (int off = 1; off < 16; off <<= 1)
      #pragma unroll
      for (int r = 0; r < 4; ++r)
        cmax[r] = fmaxf(cmax[r], __shfl_xor(cmax[r], off));
    float scl[4], rs[4];
    #pragma unroll
    for (int r = 0; r < 4; ++r) {
      float nm = fmaxf(m_r[r], cmax[r]);
      scl[r] = __expf(m_r[r] - nm);
      m_r[r] = nm;
      rs[r] = 0.f;
    }
    #pragma unroll
    for (int nt = 0; nt < 7; ++nt)
      #pragma unroll
      for (int r = 0; r < 4; ++r) {
        float p = __expf(sacc[nt][r] - m_r[r]);
        rs[r] += p;
        P_lds[wid][(lq * 4 + r) * VTS_ + nt * 16 + l16] = f2bf(p);
      }
    #pragma unroll
    for (int off = 1; off < 16; off <<= 1)
      #pragma unroll
      for (int r = 0; r < 4; ++r)
        rs[r] += __shfl_xor(rs[r], off);
    #pragma unroll
    for (int r = 0; r < 4; ++r) l_r[r] = l_r[r] * scl[r] + rs[r];
    #pragma unroll
    for (int nt = 0; nt < 5; ++nt)
      #pragma unroll
      for (int r = 0; r < 4; ++r) O[nt][r] *= scl[r];
    #pragma unroll
    for (int ks = 0; ks < 4; ++ks) {
      bf16x8 pf = *(const bf16x8*)&P_lds[wid][l16 * VTS_ + ks * 32 + lq * 8];
      #pragma unroll
      for (int nt = 0; nt < 5; ++nt) {
        bf16x8 vf = *(const bf16x8*)&Vt_lds[(nt * 16 + l16) * VTS_ + ks * 32 + lq * 8];
        O[nt] = __builtin_amdgcn_mfma_f32_16x16x32_bf16(pf, vf, O[nt], 0, 0, 0);
      }
    }
    __syncthreads();
    if (c < 6) {
      #pragma unroll
      for (int i = 0; i < 4; ++i) {
        if (sval[i]) {
          *(u16x8*)&K_lds[srow[i] * AKS_ + scol[i] * 8] = kreg[i];
          #pragma unroll
          for (int e = 0; e < 8; ++e)
            Vt_lds[(scol[i] * 8 + e) * VTS_ + srow[i]] = vreg[i][e];
        }
      }
      __syncthreads();
    }
  }
  float inv[4];
  #pragma unroll
  for (int r = 0; r < 4; ++r) inv[r] = 1.f / l_r[r];
  #pragma unroll
  for (int nt = 0; nt < 5; ++nt) {
    int d = nt * 16 + l16;
    if (d >= HD_) continue;
    #pragma unroll
    for (int r = 0; r < 4; ++r) {
      int a = wid * 16 + lq * 4 + r;
      if (a < AGENT_)
        agent_v[(((size_t)b * HEADS_ + h) * AGENT_ + a) * HD_ + d] = O[nt][r] * inv[r];
    }
  }
}

// ---------------- q attention (round-11 proven form) ----------------
__global__ __launch_bounds__(256) void q_attn_kernel(
    const ushort_t* __restrict__ qkvb, const float* __restrict__ agent,
    const float* __restrict__ agent_v, const float* __restrict__ qbias,
    float* __restrict__ xf) {
  __shared__ float ag_t[HD_ * 52];
  __shared__ float av_t[HD_ * 52];
  const int tid = threadIdx.x;
  const int h = blockIdx.y, b = blockIdx.z;
  for (int t = tid; t < AGENT_ * HD_; t += 256) {
    int a = t / HD_, d = t % HD_;
    ag_t[d * 52 + a] = agent[((size_t)b * AGENT_ + a) * C_ + h * HD_ + d];
    av_t[d * 52 + a] = agent_v[(((size_t)b * HEADS_ + h) * AGENT_ + a) * HD_ + d];
  }
  __syncthreads();
  const int n = blockIdx.x * 256 + tid;
  if (n >= N_) return;
  const ushort_t* qp = qkvb + ((size_t)b * N_ + n) * QKVW_ + h * HD_;
  const float* qb = qbias + ((size_t)h * N_ + n) * AGENT_;
  float lg[AGENT_];
  #pragma unroll
  for (int a = 0; a < AGENT_; ++a) lg[a] = qb[a];
  for (int d = 0; d < HD_; ++d) {
    float qd = bf2f(qp[d]) * SCALE_;
    #pragma unroll
    for (int a = 0; a < AGENT_; ++a) lg[a] += qd * ag_t[d * 52 + a];
  }
  float mx = -1e30f;
  #pragma unroll
  for (int a = 0; a < AGENT_; ++a) mx = fmaxf(mx, lg[a]);
  float s = 0.f;
  #pragma unroll
  for (int a = 0; a < AGENT_; ++a) { lg[a] = __expf(lg[a] - mx); s += lg[a]; }
  float inv = 1.f / s;
  #pragma unroll
  for (int a = 0; a < AGENT_; ++a) lg[a] *= inv;
  float* op = xf + ((size_t)b * N_ + n) * C_ + h * HD_;
  for (int d = 0; d < HD_; ++d) {
    float acc = 0.f;
    #pragma unroll
    for (int a = 0; a < AGENT_; ++a) acc += lg[a] * av_t[d * 52 + a];
    op[d] = acc;
  }
}

// ---------------- depthwise conv + BN + ReLU (2ch/thread, XCD swizzle) ------
__global__ __launch_bounds__(288) void dwc_kernel(
    const ushort_t* __restrict__ qkvb, const float* __restrict__ w,
    const float* __restrict__ bias, const float* __restrict__ gamma,
    const float* __restrict__ beta, const float* __restrict__ mean,
    const float* __restrict__ var, float* __restrict__ xf) {
  int lin = blockIdx.x;
  const int bn = (lin & 7) * 3136 + (lin >> 3);   // 25088 = 8*3136, bijective
  const int b = bn / N_, n = bn % N_;
  const int y = n / W_, x = n % W_;
  const int c0 = threadIdx.x * 2;
  float a0 = 0.f, a1 = 0.f;
  #pragma unroll
  for (int ky = 0; ky < 3; ++ky) {
    int yy = y + ky - 1;
    if (yy < 0 || yy >= H_) continue;
    #pragma unroll
    for (int kx = 0; kx < 3; ++kx) {
      int xx = x + kx - 1;
      if (xx < 0 || xx >= W_) continue;
      unsigned v = *(const unsigned*)(qkvb + ((size_t)b * N_ + yy * W_ + xx) * QKVW_ + 2 * C_ + c0);
      a0 += w[c0 * 9 + ky * 3 + kx] * bf2f((ushort_t)(v & 0xffffu));
      a1 += w[(c0 + 1) * 9 + ky * 3 + kx] * bf2f((ushort_t)(v >> 16));
    }
  }
  float s0 = gamma[c0] * rsqrtf(var[c0] + 1e-5f);
  float s1 = gamma[c0 + 1] * rsqrtf(var[c0 + 1] + 1e-5f);
  float r0 = fmaxf((a0 + bias[c0] - mean[c0]) * s0 + beta[c0], 0.f);
  float r1 = fmaxf((a1 + bias[c0 + 1] - mean[c0 + 1]) * s1 + beta[c0 + 1], 0.f);
  float2* xp = (float2*)&xf[(size_t)bn * C_ + c0];
  float2 old = *xp;
  old.x += r0; old.y += r1;
  *xp = old;
}

extern "C" void kernel_launch(void* const* d_in, const int* in_sizes, int n_in,
                              void* d_out, int out_size, void* d_ws, size_t ws_size,
                              hipStream_t stream) {
  const float* x        = (const float*)d_in[0];
  const float* Wq       = (const float*)d_in[3];
  const float* Wkv      = (const float*)d_in[4];
  const float* an_bias  = (const float*)d_in[5];
  const float* na_bias  = (const float*)d_in[6];
  const float* ah_bias  = (const float*)d_in[7];
  const float* aw_bias  = (const float*)d_in[8];
  const float* ha_bias  = (const float*)d_in[9];
  const float* wa_bias  = (const float*)d_in[10];
  const float* dwc_w    = (const float*)d_in[11];
  const float* dwc_b    = (const float*)d_in[12];
  const float* bn_gamma = (const float*)d_in[13];
  const float* bn_beta  = (const float*)d_in[14];
  const float* bn_mean  = (const float*)d_in[15];
  const float* bn_var   = (const float*)d_in[16];
  const float* base_w   = (const float*)d_in[17];
  const float* spline_w = (const float*)d_in[18];
  const float* spline_s = (const float*)d_in[19];

  char* ws = (char*)d_ws;
  ushort_t* qkvb   = (ushort_t*)(ws + 0);
  ushort_t* xbf    = (ushort_t*)(ws + 86704128);
  ushort_t* wbf    = (ushort_t*)(ws + 115605504);
  ushort_t* bpackb = (ushort_t*)(ws + 117596160);
  float* agent     = (float*)(ws + 123568128);
  float* agent_v   = (float*)(ws + 127180800);
  float* abias     = (float*)(ws + 130793472);
  float* qbias     = (float*)(ws + 132022784);
  float* xf        = (float*)(ws + 133252096);
  float* out       = (float*)d_out;

  prep_kernel<<<dim3(PREP_TOTAL_), dim3(256), 0, stream>>>(
      x, xbf, Wq, Wkv, wbf, base_w, spline_w, spline_s, bpackb,
      an_bias, na_bias, ah_bias, aw_bias, ha_bias, wa_bias, abias, qbias);
  mfma_qkv_kernel<<<dim3(1764), dim3(512), 0, stream>>>(xbf, wbf, qkvb);
  agent_pool_kernel<<<dim3(B_ * AGENT_), dim3(C_), 0, stream>>>(qkvb, agent);
  agent_attn_mfma_kernel<<<dim3(B_ * HEADS_), dim3(256), 0, stream>>>(
      agent, qkvb, abias, agent_v);
  q_attn_kernel<<<dim3(4, HEADS_, B_), dim3(256), 0, stream>>>(
      qkvb, agent, agent_v, qbias, xf);
  dwc_kernel<<<dim3(M_), dim3(288), 0, stream>>>(
      qkvb, dwc_w, dwc_b, bn_gamma, bn_beta, bn_mean, bn_var, xf);
  kan_mfma_kernel<<<dim3(588), dim3(512), 0, stream>>>(xf, bpackb, out);
}

// Round 16
// 611.703 us; speedup vs baseline: 1.6400x; 1.0063x over previous
//
#include <hip/hip_runtime.h>
#include <hip/hip_bf16.h>
#include <math.h>

#define B_ 32
#define N_ 784
#define C_ 576
#define H_ 28
#define W_ 28
#define HEADS_ 8
#define HD_ 72
#define AGENT_ 49
#define M_ (B_ * N_)            // 25088
#define KTOT_ 5184              // 576 silu + 576*8 spline
#define QKVW_ 1728
#define SCALE_ 0.11785113019775793f

// BK=64 swizzled LDS: row stride 64 elems (128 B); 16B chunks XOR'd by row&7.
// Verified conflict-free (rounds 7-15: SQ_LDS_BANK_CONFLICT = 0).
#define SWZ64(row, chunk) (((row) << 6) + ((((chunk) ^ ((row) & 7))) << 3))

typedef unsigned short ushort_t;
typedef __attribute__((ext_vector_type(8))) unsigned short u16x8;
typedef __attribute__((ext_vector_type(8))) __bf16 bf16x8;
typedef __attribute__((ext_vector_type(4))) float f32x4;
typedef __attribute__((ext_vector_type(4))) unsigned u32x4;

__device__ __forceinline__ ushort_t f2bf(float f) {
  union { float f; unsigned u; } v; v.f = f;
  unsigned r = v.u + 0x7fffu + ((v.u >> 16) & 1u);
  return (ushort_t)(r >> 16);
}
__device__ __forceinline__ float bf2f(ushort_t u) {
  union { unsigned u; float f; } v; v.u = ((unsigned)u) << 16;
  return v.f;
}
__device__ __forceinline__ unsigned pack2(float lo, float hi) {
  __bf16 a = (__bf16)lo, b = (__bf16)hi;
  unsigned short ua = __builtin_bit_cast(unsigned short, a);
  unsigned short ub = __builtin_bit_cast(unsigned short, b);
  return (unsigned)ua | ((unsigned)ub << 16);
}

// ---------------- merged prep: bias | pack_b(frag) | pack_w | convert_x -----
__device__ __forceinline__ float bilerp7(const float* __restrict__ Bsrc, int y, int x) {
  float sy = y * 0.25f - 0.375f;
  float sx = x * 0.25f - 0.375f;
  float fy0 = floorf(sy), fx0 = floorf(sx);
  int y0 = (int)fy0, x0 = (int)fx0;
  float fy = sy - fy0, fx = sx - fx0;
  int y0c = min(6, max(0, y0)), y1c = min(6, max(0, y0 + 1));
  int x0c = min(6, max(0, x0)), x1c = min(6, max(0, x0 + 1));
  float v00 = Bsrc[y0c * 7 + x0c], v01 = Bsrc[y0c * 7 + x1c];
  float v10 = Bsrc[y1c * 7 + x0c], v11 = Bsrc[y1c * 7 + x1c];
  return (1.f - fy) * ((1.f - fx) * v00 + fx * v01)
       + fy * ((1.f - fx) * v10 + fx * v11);
}

#define PREP_BIAS_   1201
#define PREP_PACKB_  (PREP_BIAS_ + 576)    // 1777
#define PREP_PACKW_  (PREP_PACKB_ + 512)   // 2289
#define PREP_TOTAL_  (PREP_PACKW_ + 1024)  // 3313

__global__ __launch_bounds__(256) void prep_kernel(
    const float* __restrict__ x, ushort_t* __restrict__ xbf,
    const float* __restrict__ Wq, const float* __restrict__ Wkv,
    ushort_t* __restrict__ wbf,
    const float* __restrict__ base_w, const float* __restrict__ spline_w,
    const float* __restrict__ spline_s, ushort_t* __restrict__ bfrag,
    const float* __restrict__ an_bias, const float* __restrict__ na_bias,
    const float* __restrict__ ah_bias, const float* __restrict__ aw_bias,
    const float* __restrict__ ha_bias, const float* __restrict__ wa_bias,
    float* __restrict__ abias, float* __restrict__ qbias) {
  const int blk = blockIdx.x, tid = threadIdx.x;
  if (blk < PREP_BIAS_) {
    int idx = blk * 256 + tid;
    if (idx >= HEADS_ * AGENT_ * N_) return;
    int n = idx % N_;
    int ha = idx / N_;
    int h = ha / AGENT_, a = ha % AGENT_;
    int y = n / W_, xx = n % W_;
    float pb1 = bilerp7(an_bias + (size_t)ha * 49, y, xx);
    float pb2 = ah_bias[ha * H_ + y] + aw_bias[ha * W_ + xx];
    abias[(size_t)ha * N_ + n] = pb1 + pb2;
    float ab1 = bilerp7(na_bias + (size_t)ha * 49, y, xx);
    float ab2 = ha_bias[(h * H_ + y) * AGENT_ + a] + wa_bias[(h * W_ + xx) * AGENT_ + a];
    qbias[((size_t)h * N_ + n) * AGENT_ + a] = ab1 + ab2;
  } else if (blk < PREP_PACKB_) {
    // KAN B packed in MFMA-fragment order:
    // slot = (((nt*4+wn)*81 + s)*2 + ks)*3 + fn ; addr = slot*512 + lane*8 + e
    // lane = ((k%32)/8)*16 + (row%16); e = k%8
    int o = blk - PREP_BIAS_;
    const int nt = o / 192, ro = o % 192;
    const int wn = ro / 48, fr = ro % 48;
    const int fn = fr / 16, l16f = fr % 16;
    for (int j = tid; j < KTOT_; j += 256) {
      float v;
      if (j < C_) {
        v = base_w[(size_t)o * C_ + j];
      } else {
        int jj = j - C_;
        int i = jj >> 3, kk = jj & 7;
        v = spline_w[((size_t)o * C_ + i) * 8 + kk] * spline_s[(size_t)o * C_ + i];
      }
      int s = j >> 6, kk = j & 63;
      int ks = kk >> 5, lq8 = (kk & 31) >> 3, e = j & 7;
      int lane = lq8 * 16 + l16f;
      size_t addr = ((((size_t)(nt * 4 + wn) * 81 + s) * 2 + ks) * 3 + fn) * 512
                    + lane * 8 + e;
      bfrag[addr] = f2bf(v);
    }
  } else if (blk < PREP_PACKW_) {
    int total = QKVW_ * C_;
    for (int i = (blk - PREP_PACKB_) * 256 + tid; i < total; i += 512 * 256) {
      int j = i / C_, k = i % C_;
      float v = (j < C_) ? Wq[(size_t)j * C_ + k] : Wkv[(size_t)(j - C_) * C_ + k];
      wbf[i] = f2bf(v);
    }
  } else {
    const int total8 = M_ * C_ / 8;
    for (int i = (blk - PREP_PACKW_) * 256 + tid; i < total8; i += 1024 * 256) {
      f32x4 a = *(const f32x4*)(x + i * 8);
      f32x4 b = *(const f32x4*)(x + i * 8 + 4);
      u16x8 o;
      o[0]=f2bf(a[0]); o[1]=f2bf(a[1]); o[2]=f2bf(a[2]); o[3]=f2bf(a[3]);
      o[4]=f2bf(b[0]); o[5]=f2bf(b[1]); o[6]=f2bf(b[2]); o[7]=f2bf(b[3]);
      *(u16x8*)(xbf + i * 8) = o;
    }
  }
}

// ---------------- MFMA GEMM: qkv (8 waves, BK=64, write/load-first order) ---
// grid: 1764 = 196 row-tiles x 9 col-tiles (col fastest); 1764 = 8*220+4
__global__ __launch_bounds__(512, 4) void mfma_qkv_kernel(
    const ushort_t* __restrict__ A, const ushort_t* __restrict__ Bt,
    ushort_t* __restrict__ out) {
  __shared__ ushort_t Asl[2][128 * 64];   // 32 KB
  __shared__ ushort_t Bsl[2][192 * 64];   // 48 KB
  const int tid = threadIdx.x;
  const int lane = tid & 63, wid = tid >> 6;
  const int wm = wid >> 2, wn = wid & 3;
  const int l16 = lane & 15, lq = lane >> 4;

  int lin = blockIdx.x;
  const int q = 220, r = 4;          // 1764 = 8*220+4
  int xcd = lin & 7;
  int wg = (xcd < r ? xcd * (q + 1) : r * (q + 1) + (xcd - r) * q) + (lin >> 3);
  const int m0 = (wg / 9) * 128, n0 = (wg % 9) * 192;

  const int srowi = tid >> 3;        // 0..63
  const int chk = tid & 7;           // 0..7

  const ushort_t* arow0 = A + (size_t)(m0 + srowi) * C_ + chk * 8;
  const ushort_t* arow1 = arow0 + (size_t)64 * C_;
  const ushort_t* brow0 = Bt + (size_t)(n0 + srowi) * C_ + chk * 8;
  const ushort_t* brow1 = brow0 + (size_t)64 * C_;
  const ushort_t* brow2 = brow0 + (size_t)128 * C_;

  const int aW0 = SWZ64(srowi, chk), aW1 = SWZ64(srowi + 64, chk);
  const int bW0 = SWZ64(srowi, chk), bW1 = SWZ64(srowi + 64, chk),
            bW2 = SWZ64(srowi + 128, chk);

  f32x4 acc[4][3] = {};
  u16x8 ar0, ar1, br0, br1, br2;

  // prologue: step0 load + write buf0, step1 load
  ar0 = *(const u16x8*)(arow0);
  ar1 = *(const u16x8*)(arow1);
  br0 = *(const u16x8*)(brow0);
  br1 = *(const u16x8*)(brow1);
  br2 = *(const u16x8*)(brow2);
  *(u16x8*)&Asl[0][aW0] = ar0;
  *(u16x8*)&Asl[0][aW1] = ar1;
  *(u16x8*)&Bsl[0][bW0] = br0;
  *(u16x8*)&Bsl[0][bW1] = br1;
  *(u16x8*)&Bsl[0][bW2] = br2;
  ar0 = *(const u16x8*)(arow0 + 64);
  ar1 = *(const u16x8*)(arow1 + 64);
  br0 = *(const u16x8*)(brow0 + 64);
  br1 = *(const u16x8*)(brow1 + 64);
  br2 = *(const u16x8*)(brow2 + 64);
  __syncthreads();

  const int NSTEP = C_ / 64;   // 9
  for (int s = 0; s < NSTEP; ++s) {
    const int cur = s & 1;
    if (s + 1 < NSTEP) {
      const int nxt = cur ^ 1;
      *(u16x8*)&Asl[nxt][aW0] = ar0;
      *(u16x8*)&Asl[nxt][aW1] = ar1;
      *(u16x8*)&Bsl[nxt][bW0] = br0;
      *(u16x8*)&Bsl[nxt][bW1] = br1;
      *(u16x8*)&Bsl[nxt][bW2] = br2;
      if (s + 2 < NSTEP) {
        const int kl = (s + 2) * 64;
        ar0 = *(const u16x8*)(arow0 + kl);
        ar1 = *(const u16x8*)(arow1 + kl);
        br0 = *(const u16x8*)(brow0 + kl);
        br1 = *(const u16x8*)(brow1 + kl);
        br2 = *(const u16x8*)(brow2 + kl);
      }
    }
    #pragma unroll
    for (int ks = 0; ks < 2; ++ks) {
      bf16x8 af[4], bfr[3];
      #pragma unroll
      for (int fm = 0; fm < 4; ++fm)
        af[fm] = *(const bf16x8*)&Asl[cur][SWZ64(wm * 64 + fm * 16 + l16, ks * 4 + lq)];
      #pragma unroll
      for (int fn = 0; fn < 3; ++fn)
        bfr[fn] = *(const bf16x8*)&Bsl[cur][SWZ64(wn * 48 + fn * 16 + l16, ks * 4 + lq)];
      #pragma unroll
      for (int fm = 0; fm < 4; ++fm)
        #pragma unroll
        for (int fn = 0; fn < 3; ++fn)
          acc[fm][fn] = __builtin_amdgcn_mfma_f32_16x16x32_bf16(
              af[fm], bfr[fn], acc[fm][fn], 0, 0, 0);
    }
    __syncthreads();
  }
  #pragma unroll
  for (int fm = 0; fm < 4; ++fm) {
    #pragma unroll
    for (int fn = 0; fn < 3; ++fn) {
      int col = n0 + wn * 48 + fn * 16 + l16;
      #pragma unroll
      for (int r2 = 0; r2 < 4; ++r2) {
        int row = m0 + wm * 64 + fm * 16 + lq * 4 + r2;
        out[(size_t)row * QKVW_ + col] = f2bf(acc[fm][fn][r2]);
      }
    }
  }
}

// ---------------- KAN A-operand generation (funnel-shift placement) --------
__device__ __forceinline__ u32x4 basesPack(float xv) {
  float s = __fmaf_rn(xv, 2.5f, 5.5f);
  float tf = floorf(s);
  int t = (int)tf;
  float u = s - tf;
  float u2 = u * u, u3 = u2 * u, um = 1.f - u;
  float p0 = u3 * (1.f / 6.f);
  float p1 = __fmaf_rn(u3, -0.5f, __fmaf_rn(u2, 0.5f, __fmaf_rn(u, 0.5f, 1.f / 6.f)));
  float p2 = __fmaf_rn(u3, 0.5f, __fmaf_rn(u2, -1.f, 2.f / 3.f));
  float p3 = um * um * um * (1.f / 6.f);
  unsigned lo = pack2(p3, p2);          // slot0=p3, slot1=p2
  unsigned hi = pack2(p1, p0);          // slot2=p1, slot3=p0
  unsigned long long packed = ((unsigned long long)hi << 32) | (unsigned long long)lo;
  int sh = t - 3;
  int ba = sh << 4;
  unsigned long long shl_lo = packed << (ba & 63);
  unsigned long long shr_sp = packed >> ((64 - ba) & 63);
  unsigned long long shl_hi = packed << ((ba - 64) & 63);
  unsigned long long shr_ng = packed >> ((-ba) & 63);
  unsigned long long Olo = (sh < 0) ? shr_ng : ((sh < 4) ? shl_lo : 0ull);
  unsigned long long Ohi = (sh <= 0) ? 0ull : ((sh < 4) ? shr_sp : shl_hi);
  if (t < 0 || t > 10) { Olo = 0ull; Ohi = 0ull; }
  u32x4 o;
  o[0] = (unsigned)Olo; o[1] = (unsigned)(Olo >> 32);
  o[2] = (unsigned)Ohi; o[3] = (unsigned)(Ohi >> 32);
  return o;
}

__device__ __forceinline__ u32x4 siluPack(const float* xv) {
  u32x4 o;
  #pragma unroll
  for (int e = 0; e < 4; ++e) {
    float v0 = xv[2 * e], v1 = xv[2 * e + 1];
    float s0 = v0 / (1.f + __expf(-v0));
    float s1 = v1 / (1.f + __expf(-v1));
    o[e] = pack2(s0, s1);
  }
  return o;
}

// ---------------- KAN MFMA GEMM (8 waves, BK=64, B direct from frag image) --
// A staged in LDS (swizzled dbuf); B read as coalesced per-wave fragment slots
// from the L2-resident 6MB image (lane*16B contiguous inside 1KB slot).
// LDS 80KB -> 32KB; LDS traffic/step 152KB -> 80KB.
// grid: 588 = 196 row-tiles x 3 col-tiles (col fastest); 588 = 8*73+4
__global__ __launch_bounds__(512, 4) void kan_mfma_kernel(
    const float* __restrict__ xf, const ushort_t* __restrict__ Bt,
    float* __restrict__ out) {
  __shared__ ushort_t Asl[2][128 * 64];   // 16 KB x2
  const int tid = threadIdx.x;
  const int lane = tid & 63, wid = tid >> 6;
  const int wm = wid >> 2, wn = wid & 3;
  const int l16 = lane & 15, lq = lane >> 4;

  int lin = blockIdx.x;
  const int q = 73, r = 4;           // 588 = 8*73+4
  int xcd = lin & 7;
  int wg = (xcd < r ? xcd * (q + 1) : r * (q + 1) + (xcd - r) * q) + (lin >> 3);
  const int m0 = (wg / 3) * 128, n0 = (wg % 3) * 192;

  const int srowi = tid >> 3;        // 0..63
  const int chk = tid & 7;           // 0..7

  const float* xfr0 = xf + (size_t)(m0 + srowi) * C_;
  const float* xfr1 = xfr0 + (size_t)64 * C_;
  // per-wave fragment base: slot stride per k-step = 6 slots * 512 = 3072
  const ushort_t* bfw = Bt + ((size_t)((wg % 3) * 4 + wn) * 81) * 3072 + lane * 8;

  const int aW0 = SWZ64(srowi, chk), aW1 = SWZ64(srowi + 64, chk);

  f32x4 acc[4][3] = {};
  float xv0[8], xv1[8];
  u16x8 bcur[2][3];

  // prologue: B(0) fragments; gen+write A(0); xv for step1
  #pragma unroll
  for (int ks = 0; ks < 2; ++ks)
    #pragma unroll
    for (int fn = 0; fn < 3; ++fn)
      bcur[ks][fn] = *(const u16x8*)(bfw + (ks * 3 + fn) * 512);
  {
    f32x4 a = *(const f32x4*)(xfr0 + chk * 8);
    f32x4 b = *(const f32x4*)(xfr0 + chk * 8 + 4);
    xv0[0]=a[0]; xv0[1]=a[1]; xv0[2]=a[2]; xv0[3]=a[3];
    xv0[4]=b[0]; xv0[5]=b[1]; xv0[6]=b[2]; xv0[7]=b[3];
    f32x4 c = *(const f32x4*)(xfr1 + chk * 8);
    f32x4 d = *(const f32x4*)(xfr1 + chk * 8 + 4);
    xv1[0]=c[0]; xv1[1]=c[1]; xv1[2]=c[2]; xv1[3]=c[3];
    xv1[4]=d[0]; xv1[5]=d[1]; xv1[6]=d[2]; xv1[7]=d[3];
  }
  *(u32x4*)&Asl[0][aW0] = siluPack(xv0);
  *(u32x4*)&Asl[0][aW1] = siluPack(xv1);
  {
    f32x4 a = *(const f32x4*)(xfr0 + 64 + chk * 8);
    f32x4 b = *(const f32x4*)(xfr0 + 64 + chk * 8 + 4);
    xv0[0]=a[0]; xv0[1]=a[1]; xv0[2]=a[2]; xv0[3]=a[3];
    xv0[4]=b[0]; xv0[5]=b[1]; xv0[6]=b[2]; xv0[7]=b[3];
    f32x4 c = *(const f32x4*)(xfr1 + 64 + chk * 8);
    f32x4 d = *(const f32x4*)(xfr1 + 64 + chk * 8 + 4);
    xv1[0]=c[0]; xv1[1]=c[1]; xv1[2]=c[2]; xv1[3]=c[3];
    xv1[4]=d[0]; xv1[5]=d[1]; xv1[6]=d[2]; xv1[7]=d[3];
  }
  __syncthreads();

  const int NSTEP = KTOT_ / 64;   // 81
  for (int s = 0; s < NSTEP; ++s) {
    const int cur = s & 1;
    // A(s+1): gen + ds_write nxt; xv loads for s+2
    if (s + 1 < NSTEP) {
      const int nxt = cur ^ 1;
      const int kg = (s + 1) * 64;
      u32x4 a0, a1;
      if (kg < C_) { a0 = siluPack(xv0); a1 = siluPack(xv1); }
      else         { a0 = basesPack(xv0[0]); a1 = basesPack(xv1[0]); }
      *(u32x4*)&Asl[nxt][aW0] = a0;
      *(u32x4*)&Asl[nxt][aW1] = a1;
      if (s + 2 < NSTEP) {
        const int kl = (s + 2) * 64;
        if (kl < C_) {
          f32x4 a = *(const f32x4*)(xfr0 + kl + chk * 8);
          f32x4 b = *(const f32x4*)(xfr0 + kl + chk * 8 + 4);
          xv0[0]=a[0]; xv0[1]=a[1]; xv0[2]=a[2]; xv0[3]=a[3];
          xv0[4]=b[0]; xv0[5]=b[1]; xv0[6]=b[2]; xv0[7]=b[3];
          f32x4 c = *(const f32x4*)(xfr1 + kl + chk * 8);
          f32x4 d = *(const f32x4*)(xfr1 + kl + chk * 8 + 4);
          xv1[0]=c[0]; xv1[1]=c[1]; xv1[2]=c[2]; xv1[3]=c[3];
          xv1[4]=d[0]; xv1[5]=d[1]; xv1[6]=d[2]; xv1[7]=d[3];
        } else {
          int i0 = ((kl - C_) >> 3) + chk;
          xv0[0] = xfr0[i0];
          xv1[0] = xfr1[i0];
        }
      }
    }
    // MFMA on cur: A from LDS, B from registers (loaded last iteration)
    #pragma unroll
    for (int ks = 0; ks < 2; ++ks) {
      bf16x8 af[4];
      #pragma unroll
      for (int fm = 0; fm < 4; ++fm)
        af[fm] = *(const bf16x8*)&Asl[cur][SWZ64(wm * 64 + fm * 16 + l16, ks * 4 + lq)];
      #pragma unroll
      for (int fm = 0; fm < 4; ++fm)
        #pragma unroll
        for (int fn = 0; fn < 3; ++fn)
          acc[fm][fn] = __builtin_amdgcn_mfma_f32_16x16x32_bf16(
              af[fm], __builtin_bit_cast(bf16x8, bcur[ks][fn]), acc[fm][fn], 0, 0, 0);
    }
    // reload bcur for s+1 now that MFMA consumed it; latency hides under
    // the barrier + next step's A-gen + MFMA issue.
    if (s + 1 < NSTEP) {
      const ushort_t* bs = bfw + (size_t)(s + 1) * 3072;
      #pragma unroll
      for (int ks = 0; ks < 2; ++ks)
        #pragma unroll
        for (int fn = 0; fn < 3; ++fn)
          bcur[ks][fn] = *(const u16x8*)(bs + (ks * 3 + fn) * 512);
    }
    __syncthreads();
  }
  #pragma unroll
  for (int fm = 0; fm < 4; ++fm) {
    #pragma unroll
    for (int fn = 0; fn < 3; ++fn) {
      int col = n0 + wn * 48 + fn * 16 + l16;
      #pragma unroll
      for (int r2 = 0; r2 < 4; ++r2) {
        int row = m0 + wm * 64 + fm * 16 + lq * 4 + r2;
        out[(size_t)row * C_ + col] = acc[fm][fn][r2];
      }
    }
  }
}

// ---------------- agent pooling ----------------
__global__ __launch_bounds__(576) void agent_pool_kernel(
    const ushort_t* __restrict__ qkvb, float* __restrict__ agent) {
  int ba = blockIdx.x;
  int b = ba / AGENT_, a = ba % AGENT_;
  int ay = a / 7, ax = a % 7;
  int ch = threadIdx.x;
  float s = 0.f;
  #pragma unroll
  for (int i2 = 0; i2 < 4; ++i2)
    #pragma unroll
    for (int i4 = 0; i4 < 4; ++i4)
      s += bf2f(qkvb[((size_t)b * N_ + (ay * 4 + i2) * W_ + (ax * 4 + i4)) * QKVW_ + ch]);
  agent[(size_t)ba * C_ + ch] = s * 0.0625f;
}

// ---------------- agent attention v3: MFMA flash, one block per (b,h) -------
#define AKS_ 104
#define VTS_ 136
__global__ __launch_bounds__(256) void agent_attn_mfma_kernel(
    const float* __restrict__ agent, const ushort_t* __restrict__ qkvb,
    const float* __restrict__ abias, float* __restrict__ agent_v) {
  __shared__ ushort_t A_lds[64 * AKS_];
  __shared__ ushort_t K_lds[112 * AKS_];
  __shared__ ushort_t Vt_lds[80 * VTS_];
  __shared__ ushort_t P_lds[4][16 * VTS_];
  const int tid = threadIdx.x;
  const int lane = tid & 63, wid = tid >> 6;
  const int l16 = lane & 15, lq = lane >> 4;
  const int b = blockIdx.x >> 3, h = blockIdx.x & 7;

  for (int i = tid; i < 64 * AKS_; i += 256) A_lds[i] = 0;
  for (int i = tid; i < 112 * 32; i += 256) {
    int r = i >> 5, cc = 72 + (i & 31);
    K_lds[r * AKS_ + cc] = 0;
  }
  for (int i = tid; i < 80 * VTS_; i += 256) Vt_lds[i] = 0;
  for (int i = tid; i < 4 * 16 * 24; i += 256) {
    int w = i / (16 * 24), rest = i % (16 * 24);
    int r = rest / 24, cc = 112 + rest % 24;
    P_lds[w][r * VTS_ + cc] = 0;
  }
  for (int i = tid; i < AGENT_ * HD_; i += 256) {
    int a = i / HD_, d = i % HD_;
    A_lds[a * AKS_ + d] = f2bf(agent[((size_t)b * AGENT_ + a) * C_ + h * HD_ + d]);
  }

  int srow[4], scol[4]; bool sval[4];
  #pragma unroll
  for (int i = 0; i < 4; ++i) {
    int idx = tid + i * 256;
    srow[i] = idx / 9; scol[i] = idx % 9;
    sval[i] = idx < 1008;
  }
  const ushort_t* kbase = qkvb + (size_t)b * N_ * QKVW_ + C_ + h * HD_;
  const ushort_t* vbase = qkvb + (size_t)b * N_ * QKVW_ + 2 * C_ + h * HD_;

  u16x8 kreg[4], vreg[4];
  #pragma unroll
  for (int i = 0; i < 4; ++i) {
    if (sval[i]) {
      kreg[i] = *(const u16x8*)(kbase + (size_t)srow[i] * QKVW_ + scol[i] * 8);
      vreg[i] = *(const u16x8*)(vbase + (size_t)srow[i] * QKVW_ + scol[i] * 8);
    }
  }
  #pragma unroll
  for (int i = 0; i < 4; ++i) {
    if (sval[i]) {
      *(u16x8*)&K_lds[srow[i] * AKS_ + scol[i] * 8] = kreg[i];
      #pragma unroll
      for (int e = 0; e < 8; ++e)
        Vt_lds[(scol[i] * 8 + e) * VTS_ + srow[i]] = vreg[i][e];
    }
  }
  __syncthreads();

  float m_r[4] = {-1e30f, -1e30f, -1e30f, -1e30f};
  float l_r[4] = {};
  f32x4 O[5] = {};
  const float* bias_base[4];
  #pragma unroll
  for (int r = 0; r < 4; ++r) {
    int a = wid * 16 + lq * 4 + r;
    a = min(a, AGENT_ - 1);
    bias_base[r] = abias + ((size_t)h * AGENT_ + a) * N_;
  }

  for (int c = 0; c < 7; ++c) {
    if (c < 6) {
      const size_t off = (size_t)(c + 1) * 112 * QKVW_;
      #pragma unroll
      for (int i = 0; i < 4; ++i) {
        if (sval[i]) {
          kreg[i] = *(const u16x8*)(kbase + off + (size_t)srow[i] * QKVW_ + scol[i] * 8);
          vreg[i] = *(const u16x8*)(vbase + off + (size_t)srow[i] * QKVW_ + scol[i] * 8);
        }
      }
    }
    f32x4 sacc[7] = {};
    #pragma unroll
    for (int ks = 0; ks < 3; ++ks) {
      bf16x8 af = *(const bf16x8*)&A_lds[(wid * 16 + l16) * AKS_ + ks * 32 + lq * 8];
      #pragma unroll
      for (int nt = 0; nt < 7; ++nt) {
        bf16x8 bf = *(const bf16x8*)&K_lds[(nt * 16 + l16) * AKS_ + ks * 32 + lq * 8];
        sacc[nt] = __builtin_amdgcn_mfma_f32_16x16x32_bf16(af, bf, sacc[nt], 0, 0, 0);
      }
    }
    float cmax[4] = {-1e30f, -1e30f, -1e30f, -1e30f};
    const int nb = c * 112 + l16;
    #pragma unroll
    for (int nt = 0; nt < 7; ++nt)
      #pragma unroll
      for (int r = 0; r < 4; ++r) {
        float lg = sacc[nt][r] * SCALE_ + bias_base[r][nb + nt * 16];
        sacc[nt][r] = lg;
        cmax[r] = fmaxf(cmax[r], lg);
      }
    #pragma unroll
    for (int off = 1; off < 16; off <<= 1)
      #pragma unroll
      for (int r = 0; r < 4; ++r)
        cmax[r] = fmaxf(cmax[r], __shfl_xor(cmax[r], off));
    float scl[4], rs[4];
    #pragma unroll
    for (int r = 0; r < 4; ++r) {
      float nm = fmaxf(m_r[r], cmax[r]);
      scl[r] = __expf(m_r[r] - nm);
      m_r[r] = nm;
      rs[r] = 0.f;
    }
    #pragma unroll
    for (int nt = 0; nt < 7; ++nt)
      #pragma unroll
      for (int r = 0; r < 4; ++r) {
        float p = __expf(sacc[nt][r] - m_r[r]);
        rs[r] += p;
        P_lds[wid][(lq * 4 + r) * VTS_ + nt * 16 + l16] = f2bf(p);
      }
    #pragma unroll
    for (int off = 1; off < 16; off <<= 1)
      #pragma unroll
      for (int r = 0; r < 4; ++r)
        rs[r] += __shfl_xor(rs[r], off);
    #pragma unroll
    for (int r = 0; r < 4; ++r) l_r[r] = l_r[r] * scl[r] + rs[r];
    #pragma unroll
    for (int nt = 0; nt < 5; ++nt)
      #pragma unroll
      for (int r = 0; r < 4; ++r) O[nt][r] *= scl[r];
    #pragma unroll
    for (int ks = 0; ks < 4; ++ks) {
      bf16x8 pf = *(const bf16x8*)&P_lds[wid][l16 * VTS_ + ks * 32 + lq * 8];
      #pragma unroll
      for (int nt = 0; nt < 5; ++nt) {
        bf16x8 vf = *(const bf16x8*)&Vt_lds[(nt * 16 + l16) * VTS_ + ks * 32 + lq * 8];
        O[nt] = __builtin_amdgcn_mfma_f32_16x16x32_bf16(pf, vf, O[nt], 0, 0, 0);
      }
    }
    __syncthreads();
    if (c < 6) {
      #pragma unroll
      for (int i = 0; i < 4; ++i) {
        if (sval[i]) {
          *(u16x8*)&K_lds[srow[i] * AKS_ + scol[i] * 8] = kreg[i];
          #pragma unroll
          for (int e = 0; e < 8; ++e)
            Vt_lds[(scol[i] * 8 + e) * VTS_ + srow[i]] = vreg[i][e];
        }
      }
      __syncthreads();
    }
  }
  float inv[4];
  #pragma unroll
  for (int r = 0; r < 4; ++r) inv[r] = 1.f / l_r[r];
  #pragma unroll
  for (int nt = 0; nt < 5; ++nt) {
    int d = nt * 16 + l16;
    if (d >= HD_) continue;
    #pragma unroll
    for (int r = 0; r < 4; ++r) {
      int a = wid * 16 + lq * 4 + r;
      if (a < AGENT_)
        agent_v[(((size_t)b * HEADS_ + h) * AGENT_ + a) * HD_ + d] = O[nt][r] * inv[r];
    }
  }
}

// ---------------- q attention (round-11 proven form) ----------------
__global__ __launch_bounds__(256) void q_attn_kernel(
    const ushort_t* __restrict__ qkvb, const float* __restrict__ agent,
    const float* __restrict__ agent_v, const float* __restrict__ qbias,
    float* __restrict__ xf) {
  __shared__ float ag_t[HD_ * 52];
  __shared__ float av_t[HD_ * 52];
  const int tid = threadIdx.x;
  const int h = blockIdx.y, b = blockIdx.z;
  for (int t = tid; t < AGENT_ * HD_; t += 256) {
    int a = t / HD_, d = t % HD_;
    ag_t[d * 52 + a] = agent[((size_t)b * AGENT_ + a) * C_ + h * HD_ + d];
    av_t[d * 52 + a] = agent_v[(((size_t)b * HEADS_ + h) * AGENT_ + a) * HD_ + d];
  }
  __syncthreads();
  const int n = blockIdx.x * 256 + tid;
  if (n >= N_) return;
  const ushort_t* qp = qkvb + ((size_t)b * N_ + n) * QKVW_ + h * HD_;
  const float* qb = qbias + ((size_t)h * N_ + n) * AGENT_;
  float lg[AGENT_];
  #pragma unroll
  for (int a = 0; a < AGENT_; ++a) lg[a] = qb[a];
  for (int d = 0; d < HD_; ++d) {
    float qd = bf2f(qp[d]) * SCALE_;
    #pragma unroll
    for (int a = 0; a < AGENT_; ++a) lg[a] += qd * ag_t[d * 52 + a];
  }
  float mx = -1e30f;
  #pragma unroll
  for (int a = 0; a < AGENT_; ++a) mx = fmaxf(mx, lg[a]);
  float s = 0.f;
  #pragma unroll
  for (int a = 0; a < AGENT_; ++a) { lg[a] = __expf(lg[a] - mx); s += lg[a]; }
  float inv = 1.f / s;
  #pragma unroll
  for (int a = 0; a < AGENT_; ++a) lg[a] *= inv;
  float* op = xf + ((size_t)b * N_ + n) * C_ + h * HD_;
  for (int d = 0; d < HD_; ++d) {
    float acc = 0.f;
    #pragma unroll
    for (int a = 0; a < AGENT_; ++a) acc += lg[a] * av_t[d * 52 + a];
    op[d] = acc;
  }
}

// ---------------- depthwise conv + BN + ReLU (2ch/thread, XCD swizzle) ------
__global__ __launch_bounds__(288) void dwc_kernel(
    const ushort_t* __restrict__ qkvb, const float* __restrict__ w,
    const float* __restrict__ bias, const float* __restrict__ gamma,
    const float* __restrict__ beta, const float* __restrict__ mean,
    const float* __restrict__ var, float* __restrict__ xf) {
  int lin = blockIdx.x;
  const int bn = (lin & 7) * 3136 + (lin >> 3);   // 25088 = 8*3136, bijective
  const int b = bn / N_, n = bn % N_;
  const int y = n / W_, x = n % W_;
  const int c0 = threadIdx.x * 2;
  float a0 = 0.f, a1 = 0.f;
  #pragma unroll
  for (int ky = 0; ky < 3; ++ky) {
    int yy = y + ky - 1;
    if (yy < 0 || yy >= H_) continue;
    #pragma unroll
    for (int kx = 0; kx < 3; ++kx) {
      int xx = x + kx - 1;
      if (xx < 0 || xx >= W_) continue;
      unsigned v = *(const unsigned*)(qkvb + ((size_t)b * N_ + yy * W_ + xx) * QKVW_ + 2 * C_ + c0);
      a0 += w[c0 * 9 + ky * 3 + kx] * bf2f((ushort_t)(v & 0xffffu));
      a1 += w[(c0 + 1) * 9 + ky * 3 + kx] * bf2f((ushort_t)(v >> 16));
    }
  }
  float s0 = gamma[c0] * rsqrtf(var[c0] + 1e-5f);
  float s1 = gamma[c0 + 1] * rsqrtf(var[c0 + 1] + 1e-5f);
  float r0 = fmaxf((a0 + bias[c0] - mean[c0]) * s0 + beta[c0], 0.f);
  float r1 = fmaxf((a1 + bias[c0 + 1] - mean[c0 + 1]) * s1 + beta[c0 + 1], 0.f);
  float2* xp = (float2*)&xf[(size_t)bn * C_ + c0];
  float2 old = *xp;
  old.x += r0; old.y += r1;
  *xp = old;
}

extern "C" void kernel_launch(void* const* d_in, const int* in_sizes, int n_in,
                              void* d_out, int out_size, void* d_ws, size_t ws_size,
                              hipStream_t stream) {
  const float* x        = (const float*)d_in[0];
  const float* Wq       = (const float*)d_in[3];
  const float* Wkv      = (const float*)d_in[4];
  const float* an_bias  = (const float*)d_in[5];
  const float* na_bias  = (const float*)d_in[6];
  const float* ah_bias  = (const float*)d_in[7];
  const float* aw_bias  = (const float*)d_in[8];
  const float* ha_bias  = (const float*)d_in[9];
  const float* wa_bias  = (const float*)d_in[10];
  const float* dwc_w    = (const float*)d_in[11];
  const float* dwc_b    = (const float*)d_in[12];
  const float* bn_gamma = (const float*)d_in[13];
  const float* bn_beta  = (const float*)d_in[14];
  const float* bn_mean  = (const float*)d_in[15];
  const float* bn_var   = (const float*)d_in[16];
  const float* base_w   = (const float*)d_in[17];
  const float* spline_w = (const float*)d_in[18];
  const float* spline_s = (const float*)d_in[19];

  char* ws = (char*)d_ws;
  ushort_t* qkvb   = (ushort_t*)(ws + 0);
  ushort_t* xbf    = (ushort_t*)(ws + 86704128);
  ushort_t* wbf    = (ushort_t*)(ws + 115605504);
  ushort_t* bfrag  = (ushort_t*)(ws + 117596160);
  float* agent     = (float*)(ws + 123568128);
  float* agent_v   = (float*)(ws + 127180800);
  float* abias     = (float*)(ws + 130793472);
  float* qbias     = (float*)(ws + 132022784);
  float* xf        = (float*)(ws + 133252096);
  float* out       = (float*)d_out;

  prep_kernel<<<dim3(PREP_TOTAL_), dim3(256), 0, stream>>>(
      x, xbf, Wq, Wkv, wbf, base_w, spline_w, spline_s, bfrag,
      an_bias, na_bias, ah_bias, aw_bias, ha_bias, wa_bias, abias, qbias);
  mfma_qkv_kernel<<<dim3(1764), dim3(512), 0, stream>>>(xbf, wbf, qkvb);
  agent_pool_kernel<<<dim3(B_ * AGENT_), dim3(C_), 0, stream>>>(qkvb, agent);
  agent_attn_mfma_kernel<<<dim3(B_ * HEADS_), dim3(256), 0, stream>>>(
      agent, qkvb, abias, agent_v);
  q_attn_kernel<<<dim3(4, HEADS_, B_), dim3(256), 0, stream>>>(
      qkvb, agent, agent_v, qbias, xf);
  dwc_kernel<<<dim3(M_), dim3(288), 0, stream>>>(
      qkvb, dwc_w, dwc_b, bn_gamma, bn_beta, bn_mean, bn_var, xf);
  kan_mfma_kernel<<<dim3(588), dim3(512), 0, stream>>>(xf, bfrag, out);
}

// Round 17
// 608.876 us; speedup vs baseline: 1.6476x; 1.0046x over previous
//
#include <hip/hip_runtime.h>
#include <hip/hip_bf16.h>
#include <math.h>

#define B_ 32
#define N_ 784
#define C_ 576
#define H_ 28
#define W_ 28
#define HEADS_ 8
#define HD_ 72
#define AGENT_ 49
#define M_ (B_ * N_)            // 25088
#define KTOT_ 5184              // 576 silu + 576*8 spline
#define QKVW_ 1728
#define SCALE_ 0.11785113019775793f

// BK=64 swizzled LDS: row stride 64 elems (128 B); 16B chunks XOR'd by row&7.
// Verified conflict-free (rounds 7-16: SQ_LDS_BANK_CONFLICT = 0).
#define SWZ64(row, chunk) (((row) << 6) + ((((chunk) ^ ((row) & 7))) << 3))

typedef unsigned short ushort_t;
typedef __attribute__((ext_vector_type(8))) unsigned short u16x8;
typedef __attribute__((ext_vector_type(8))) __bf16 bf16x8;
typedef __attribute__((ext_vector_type(4))) float f32x4;
typedef __attribute__((ext_vector_type(4))) unsigned u32x4;

__device__ __forceinline__ ushort_t f2bf(float f) {
  union { float f; unsigned u; } v; v.f = f;
  unsigned r = v.u + 0x7fffu + ((v.u >> 16) & 1u);
  return (ushort_t)(r >> 16);
}
__device__ __forceinline__ float bf2f(ushort_t u) {
  union { unsigned u; float f; } v; v.u = ((unsigned)u) << 16;
  return v.f;
}
__device__ __forceinline__ unsigned pack2(float lo, float hi) {
  __bf16 a = (__bf16)lo, b = (__bf16)hi;
  unsigned short ua = __builtin_bit_cast(unsigned short, a);
  unsigned short ub = __builtin_bit_cast(unsigned short, b);
  return (unsigned)ua | ((unsigned)ub << 16);
}

// ---------------- merged prep: bias | pack_b(frag) | pack_w(frag) | conv_x --
__device__ __forceinline__ float bilerp7(const float* __restrict__ Bsrc, int y, int x) {
  float sy = y * 0.25f - 0.375f;
  float sx = x * 0.25f - 0.375f;
  float fy0 = floorf(sy), fx0 = floorf(sx);
  int y0 = (int)fy0, x0 = (int)fx0;
  float fy = sy - fy0, fx = sx - fx0;
  int y0c = min(6, max(0, y0)), y1c = min(6, max(0, y0 + 1));
  int x0c = min(6, max(0, x0)), x1c = min(6, max(0, x0 + 1));
  float v00 = Bsrc[y0c * 7 + x0c], v01 = Bsrc[y0c * 7 + x1c];
  float v10 = Bsrc[y1c * 7 + x0c], v11 = Bsrc[y1c * 7 + x1c];
  return (1.f - fy) * ((1.f - fx) * v00 + fx * v01)
       + fy * ((1.f - fx) * v10 + fx * v11);
}

#define PREP_BIAS_   1201
#define PREP_PACKB_  (PREP_BIAS_ + 576)    // 1777
#define PREP_PACKW_  (PREP_PACKB_ + 1728)  // 3505
#define PREP_TOTAL_  (PREP_PACKW_ + 1024)  // 4529

__global__ __launch_bounds__(256) void prep_kernel(
    const float* __restrict__ x, ushort_t* __restrict__ xbf,
    const float* __restrict__ Wq, const float* __restrict__ Wkv,
    ushort_t* __restrict__ wfrag,
    const float* __restrict__ base_w, const float* __restrict__ spline_w,
    const float* __restrict__ spline_s, ushort_t* __restrict__ bfrag,
    const float* __restrict__ an_bias, const float* __restrict__ na_bias,
    const float* __restrict__ ah_bias, const float* __restrict__ aw_bias,
    const float* __restrict__ ha_bias, const float* __restrict__ wa_bias,
    float* __restrict__ abias, float* __restrict__ qbias) {
  const int blk = blockIdx.x, tid = threadIdx.x;
  if (blk < PREP_BIAS_) {
    int idx = blk * 256 + tid;
    if (idx >= HEADS_ * AGENT_ * N_) return;
    int n = idx % N_;
    int ha = idx / N_;
    int h = ha / AGENT_, a = ha % AGENT_;
    int y = n / W_, xx = n % W_;
    float pb1 = bilerp7(an_bias + (size_t)ha * 49, y, xx);
    float pb2 = ah_bias[ha * H_ + y] + aw_bias[ha * W_ + xx];
    abias[(size_t)ha * N_ + n] = pb1 + pb2;
    float ab1 = bilerp7(na_bias + (size_t)ha * 49, y, xx);
    float ab2 = ha_bias[(h * H_ + y) * AGENT_ + a] + wa_bias[(h * W_ + xx) * AGENT_ + a];
    qbias[((size_t)h * N_ + n) * AGENT_ + a] = ab1 + ab2;
  } else if (blk < PREP_PACKB_) {
    // KAN B in MFMA-fragment order (verified round 16):
    // slot = (((nt*4+wn)*81 + s)*2 + ks)*3 + fn ; addr = slot*512 + lane*8 + e
    int o = blk - PREP_BIAS_;
    const int nt = o / 192, ro = o % 192;
    const int wn = ro / 48, fr = ro % 48;
    const int fn = fr / 16, l16f = fr % 16;
    for (int j = tid; j < KTOT_; j += 256) {
      float v;
      if (j < C_) {
        v = base_w[(size_t)o * C_ + j];
      } else {
        int jj = j - C_;
        int i = jj >> 3, kk = jj & 7;
        v = spline_w[((size_t)o * C_ + i) * 8 + kk] * spline_s[(size_t)o * C_ + i];
      }
      int s = j >> 6, kk = j & 63;
      int ks = kk >> 5, lq8 = (kk & 31) >> 3, e = j & 7;
      int lane = lq8 * 16 + l16f;
      size_t addr = ((((size_t)(nt * 4 + wn) * 81 + s) * 2 + ks) * 3 + fn) * 512
                    + lane * 8 + e;
      bfrag[addr] = f2bf(v);
    }
  } else if (blk < PREP_PACKW_) {
    // qkv W in MFMA-fragment order (same mapping, 9 k-steps):
    // slot = (((nt*4+wn)*9 + s)*2 + ks)*3 + fn
    int o = blk - PREP_PACKB_;          // 0..1727 output row
    const int nt = o / 192, ro = o % 192;
    const int wn = ro / 48, fr = ro % 48;
    const int fn = fr / 16, l16f = fr % 16;
    for (int j = tid; j < C_; j += 256) {
      float v = (o < C_) ? Wq[(size_t)o * C_ + j]
                         : Wkv[(size_t)(o - C_) * C_ + j];
      int s = j >> 6, kk = j & 63;
      int ks = kk >> 5, lq8 = (kk & 31) >> 3, e = j & 7;
      int lane = lq8 * 16 + l16f;
      size_t addr = ((((size_t)(nt * 4 + wn) * 9 + s) * 2 + ks) * 3 + fn) * 512
                    + lane * 8 + e;
      wfrag[addr] = f2bf(v);
    }
  } else {
    const int total8 = M_ * C_ / 8;
    for (int i = (blk - PREP_PACKW_) * 256 + tid; i < total8; i += 1024 * 256) {
      f32x4 a = *(const f32x4*)(x + i * 8);
      f32x4 b = *(const f32x4*)(x + i * 8 + 4);
      u16x8 o;
      o[0]=f2bf(a[0]); o[1]=f2bf(a[1]); o[2]=f2bf(a[2]); o[3]=f2bf(a[3]);
      o[4]=f2bf(b[0]); o[5]=f2bf(b[1]); o[6]=f2bf(b[2]); o[7]=f2bf(b[3]);
      *(u16x8*)(xbf + i * 8) = o;
    }
  }
}

// ---------------- MFMA GEMM: qkv (8 waves, BK=64, W direct from frag image) -
// A staged in LDS (swizzled dbuf); W read as coalesced per-wave fragment
// slots from the L2-resident 2MB image. LDS 80KB -> 32KB.
// grid: 1764 = 196 row-tiles x 9 col-tiles (col fastest); 1764 = 8*220+4
__global__ __launch_bounds__(512, 4) void mfma_qkv_kernel(
    const ushort_t* __restrict__ A, const ushort_t* __restrict__ Bt,
    ushort_t* __restrict__ out) {
  __shared__ ushort_t Asl[2][128 * 64];   // 16 KB x2
  const int tid = threadIdx.x;
  const int lane = tid & 63, wid = tid >> 6;
  const int wm = wid >> 2, wn = wid & 3;
  const int l16 = lane & 15, lq = lane >> 4;

  int lin = blockIdx.x;
  const int q = 220, r = 4;          // 1764 = 8*220+4
  int xcd = lin & 7;
  int wg = (xcd < r ? xcd * (q + 1) : r * (q + 1) + (xcd - r) * q) + (lin >> 3);
  const int m0 = (wg / 9) * 128, n0 = (wg % 9) * 192;

  const int srowi = tid >> 3;        // 0..63
  const int chk = tid & 7;           // 0..7

  const ushort_t* arow0 = A + (size_t)(m0 + srowi) * C_ + chk * 8;
  const ushort_t* arow1 = arow0 + (size_t)64 * C_;
  // per-wave fragment base: slot stride per k-step = 6 slots * 512 = 3072
  const ushort_t* bfw = Bt + ((size_t)((wg % 9) * 4 + wn) * 9) * 3072 + lane * 8;

  const int aW0 = SWZ64(srowi, chk), aW1 = SWZ64(srowi + 64, chk);

  f32x4 acc[4][3] = {};
  u16x8 ar0, ar1;
  u16x8 bcur[2][3];

  // prologue: W(0) fragments; A(0) load+write; A(1) load
  #pragma unroll
  for (int ks = 0; ks < 2; ++ks)
    #pragma unroll
    for (int fn = 0; fn < 3; ++fn)
      bcur[ks][fn] = *(const u16x8*)(bfw + (ks * 3 + fn) * 512);
  ar0 = *(const u16x8*)(arow0);
  ar1 = *(const u16x8*)(arow1);
  *(u16x8*)&Asl[0][aW0] = ar0;
  *(u16x8*)&Asl[0][aW1] = ar1;
  ar0 = *(const u16x8*)(arow0 + 64);
  ar1 = *(const u16x8*)(arow1 + 64);
  __syncthreads();

  const int NSTEP = C_ / 64;   // 9
  for (int s = 0; s < NSTEP; ++s) {
    const int cur = s & 1;
    if (s + 1 < NSTEP) {
      const int nxt = cur ^ 1;
      *(u16x8*)&Asl[nxt][aW0] = ar0;
      *(u16x8*)&Asl[nxt][aW1] = ar1;
      if (s + 2 < NSTEP) {
        const int kl = (s + 2) * 64;
        ar0 = *(const u16x8*)(arow0 + kl);
        ar1 = *(const u16x8*)(arow1 + kl);
      }
    }
    #pragma unroll
    for (int ks = 0; ks < 2; ++ks) {
      bf16x8 af[4];
      #pragma unroll
      for (int fm = 0; fm < 4; ++fm)
        af[fm] = *(const bf16x8*)&Asl[cur][SWZ64(wm * 64 + fm * 16 + l16, ks * 4 + lq)];
      #pragma unroll
      for (int fm = 0; fm < 4; ++fm)
        #pragma unroll
        for (int fn = 0; fn < 3; ++fn)
          acc[fm][fn] = __builtin_amdgcn_mfma_f32_16x16x32_bf16(
              af[fm], __builtin_bit_cast(bf16x8, bcur[ks][fn]), acc[fm][fn], 0, 0, 0);
    }
    // reload W fragments for s+1 (latency hides under barrier + next MFMA)
    if (s + 1 < NSTEP) {
      const ushort_t* bs = bfw + (size_t)(s + 1) * 3072;
      #pragma unroll
      for (int ks = 0; ks < 2; ++ks)
        #pragma unroll
        for (int fn = 0; fn < 3; ++fn)
          bcur[ks][fn] = *(const u16x8*)(bs + (ks * 3 + fn) * 512);
    }
    __syncthreads();
  }
  #pragma unroll
  for (int fm = 0; fm < 4; ++fm) {
    #pragma unroll
    for (int fn = 0; fn < 3; ++fn) {
      int col = n0 + wn * 48 + fn * 16 + l16;
      #pragma unroll
      for (int r2 = 0; r2 < 4; ++r2) {
        int row = m0 + wm * 64 + fm * 16 + lq * 4 + r2;
        out[(size_t)row * QKVW_ + col] = f2bf(acc[fm][fn][r2]);
      }
    }
  }
}

// ---------------- KAN A-operand generation (funnel-shift placement) --------
__device__ __forceinline__ u32x4 basesPack(float xv) {
  float s = __fmaf_rn(xv, 2.5f, 5.5f);
  float tf = floorf(s);
  int t = (int)tf;
  float u = s - tf;
  float u2 = u * u, u3 = u2 * u, um = 1.f - u;
  float p0 = u3 * (1.f / 6.f);
  float p1 = __fmaf_rn(u3, -0.5f, __fmaf_rn(u2, 0.5f, __fmaf_rn(u, 0.5f, 1.f / 6.f)));
  float p2 = __fmaf_rn(u3, 0.5f, __fmaf_rn(u2, -1.f, 2.f / 3.f));
  float p3 = um * um * um * (1.f / 6.f);
  unsigned lo = pack2(p3, p2);          // slot0=p3, slot1=p2
  unsigned hi = pack2(p1, p0);          // slot2=p1, slot3=p0
  unsigned long long packed = ((unsigned long long)hi << 32) | (unsigned long long)lo;
  int sh = t - 3;
  int ba = sh << 4;
  unsigned long long shl_lo = packed << (ba & 63);
  unsigned long long shr_sp = packed >> ((64 - ba) & 63);
  unsigned long long shl_hi = packed << ((ba - 64) & 63);
  unsigned long long shr_ng = packed >> ((-ba) & 63);
  unsigned long long Olo = (sh < 0) ? shr_ng : ((sh < 4) ? shl_lo : 0ull);
  unsigned long long Ohi = (sh <= 0) ? 0ull : ((sh < 4) ? shr_sp : shl_hi);
  if (t < 0 || t > 10) { Olo = 0ull; Ohi = 0ull; }
  u32x4 o;
  o[0] = (unsigned)Olo; o[1] = (unsigned)(Olo >> 32);
  o[2] = (unsigned)Ohi; o[3] = (unsigned)(Ohi >> 32);
  return o;
}

__device__ __forceinline__ u32x4 siluPack(const float* xv) {
  u32x4 o;
  #pragma unroll
  for (int e = 0; e < 4; ++e) {
    float v0 = xv[2 * e], v1 = xv[2 * e + 1];
    float s0 = v0 / (1.f + __expf(-v0));
    float s1 = v1 / (1.f + __expf(-v1));
    o[e] = pack2(s0, s1);
  }
  return o;
}

// ---------------- KAN MFMA GEMM (8 waves, BK=64, B direct from frag image) --
// grid: 588 = 196 row-tiles x 3 col-tiles (col fastest); 588 = 8*73+4
__global__ __launch_bounds__(512, 4) void kan_mfma_kernel(
    const float* __restrict__ xf, const ushort_t* __restrict__ Bt,
    float* __restrict__ out) {
  __shared__ ushort_t Asl[2][128 * 64];   // 16 KB x2
  const int tid = threadIdx.x;
  const int lane = tid & 63, wid = tid >> 6;
  const int wm = wid >> 2, wn = wid & 3;
  const int l16 = lane & 15, lq = lane >> 4;

  int lin = blockIdx.x;
  const int q = 73, r = 4;           // 588 = 8*73+4
  int xcd = lin & 7;
  int wg = (xcd < r ? xcd * (q + 1) : r * (q + 1) + (xcd - r) * q) + (lin >> 3);
  const int m0 = (wg / 3) * 128, n0 = (wg % 3) * 192;

  const int srowi = tid >> 3;        // 0..63
  const int chk = tid & 7;           // 0..7

  const float* xfr0 = xf + (size_t)(m0 + srowi) * C_;
  const float* xfr1 = xfr0 + (size_t)64 * C_;
  const ushort_t* bfw = Bt + ((size_t)((wg % 3) * 4 + wn) * 81) * 3072 + lane * 8;

  const int aW0 = SWZ64(srowi, chk), aW1 = SWZ64(srowi + 64, chk);

  f32x4 acc[4][3] = {};
  float xv0[8], xv1[8];
  u16x8 bcur[2][3];

  // prologue: B(0) fragments; gen+write A(0); xv for step1
  #pragma unroll
  for (int ks = 0; ks < 2; ++ks)
    #pragma unroll
    for (int fn = 0; fn < 3; ++fn)
      bcur[ks][fn] = *(const u16x8*)(bfw + (ks * 3 + fn) * 512);
  {
    f32x4 a = *(const f32x4*)(xfr0 + chk * 8);
    f32x4 b = *(const f32x4*)(xfr0 + chk * 8 + 4);
    xv0[0]=a[0]; xv0[1]=a[1]; xv0[2]=a[2]; xv0[3]=a[3];
    xv0[4]=b[0]; xv0[5]=b[1]; xv0[6]=b[2]; xv0[7]=b[3];
    f32x4 c = *(const f32x4*)(xfr1 + chk * 8);
    f32x4 d = *(const f32x4*)(xfr1 + chk * 8 + 4);
    xv1[0]=c[0]; xv1[1]=c[1]; xv1[2]=c[2]; xv1[3]=c[3];
    xv1[4]=d[0]; xv1[5]=d[1]; xv1[6]=d[2]; xv1[7]=d[3];
  }
  *(u32x4*)&Asl[0][aW0] = siluPack(xv0);
  *(u32x4*)&Asl[0][aW1] = siluPack(xv1);
  {
    f32x4 a = *(const f32x4*)(xfr0 + 64 + chk * 8);
    f32x4 b = *(const f32x4*)(xfr0 + 64 + chk * 8 + 4);
    xv0[0]=a[0]; xv0[1]=a[1]; xv0[2]=a[2]; xv0[3]=a[3];
    xv0[4]=b[0]; xv0[5]=b[1]; xv0[6]=b[2]; xv0[7]=b[3];
    f32x4 c = *(const f32x4*)(xfr1 + 64 + chk * 8);
    f32x4 d = *(const f32x4*)(xfr1 + 64 + chk * 8 + 4);
    xv1[0]=c[0]; xv1[1]=c[1]; xv1[2]=c[2]; xv1[3]=c[3];
    xv1[4]=d[0]; xv1[5]=d[1]; xv1[6]=d[2]; xv1[7]=d[3];
  }
  __syncthreads();

  const int NSTEP = KTOT_ / 64;   // 81
  for (int s = 0; s < NSTEP; ++s) {
    const int cur = s & 1;
    // A(s+1): gen + ds_write nxt; xv loads for s+2
    if (s + 1 < NSTEP) {
      const int nxt = cur ^ 1;
      const int kg = (s + 1) * 64;
      u32x4 a0, a1;
      if (kg < C_) { a0 = siluPack(xv0); a1 = siluPack(xv1); }
      else         { a0 = basesPack(xv0[0]); a1 = basesPack(xv1[0]); }
      *(u32x4*)&Asl[nxt][aW0] = a0;
      *(u32x4*)&Asl[nxt][aW1] = a1;
      if (s + 2 < NSTEP) {
        const int kl = (s + 2) * 64;
        if (kl < C_) {
          f32x4 a = *(const f32x4*)(xfr0 + kl + chk * 8);
          f32x4 b = *(const f32x4*)(xfr0 + kl + chk * 8 + 4);
          xv0[0]=a[0]; xv0[1]=a[1]; xv0[2]=a[2]; xv0[3]=a[3];
          xv0[4]=b[0]; xv0[5]=b[1]; xv0[6]=b[2]; xv0[7]=b[3];
          f32x4 c = *(const f32x4*)(xfr1 + kl + chk * 8);
          f32x4 d = *(const f32x4*)(xfr1 + kl + chk * 8 + 4);
          xv1[0]=c[0]; xv1[1]=c[1]; xv1[2]=c[2]; xv1[3]=c[3];
          xv1[4]=d[0]; xv1[5]=d[1]; xv1[6]=d[2]; xv1[7]=d[3];
        } else {
          int i0 = ((kl - C_) >> 3) + chk;
          xv0[0] = xfr0[i0];
          xv1[0] = xfr1[i0];
        }
      }
    }
    // MFMA on cur: A from LDS, B from registers (loaded last iteration)
    #pragma unroll
    for (int ks = 0; ks < 2; ++ks) {
      bf16x8 af[4];
      #pragma unroll
      for (int fm = 0; fm < 4; ++fm)
        af[fm] = *(const bf16x8*)&Asl[cur][SWZ64(wm * 64 + fm * 16 + l16, ks * 4 + lq)];
      #pragma unroll
      for (int fm = 0; fm < 4; ++fm)
        #pragma unroll
        for (int fn = 0; fn < 3; ++fn)
          acc[fm][fn] = __builtin_amdgcn_mfma_f32_16x16x32_bf16(
              af[fm], __builtin_bit_cast(bf16x8, bcur[ks][fn]), acc[fm][fn], 0, 0, 0);
    }
    // reload bcur for s+1 now that MFMA consumed it
    if (s + 1 < NSTEP) {
      const ushort_t* bs = bfw + (size_t)(s + 1) * 3072;
      #pragma unroll
      for (int ks = 0; ks < 2; ++ks)
        #pragma unroll
        for (int fn = 0; fn < 3; ++fn)
          bcur[ks][fn] = *(const u16x8*)(bs + (ks * 3 + fn) * 512);
    }
    __syncthreads();
  }
  #pragma unroll
  for (int fm = 0; fm < 4; ++fm) {
    #pragma unroll
    for (int fn = 0; fn < 3; ++fn) {
      int col = n0 + wn * 48 + fn * 16 + l16;
      #pragma unroll
      for (int r2 = 0; r2 < 4; ++r2) {
        int row = m0 + wm * 64 + fm * 16 + lq * 4 + r2;
        out[(size_t)row * C_ + col] = acc[fm][fn][r2];
      }
    }
  }
}

// ---------------- agent pooling ----------------
__global__ __launch_bounds__(576) void agent_pool_kernel(
    const ushort_t* __restrict__ qkvb, float* __restrict__ agent) {
  int ba = blockIdx.x;
  int b = ba / AGENT_, a = ba % AGENT_;
  int ay = a / 7, ax = a % 7;
  int ch = threadIdx.x;
  float s = 0.f;
  #pragma unroll
  for (int i2 = 0; i2 < 4; ++i2)
    #pragma unroll
    for (int i4 = 0; i4 < 4; ++i4)
      s += bf2f(qkvb[((size_t)b * N_ + (ay * 4 + i2) * W_ + (ax * 4 + i4)) * QKVW_ + ch]);
  agent[(size_t)ba * C_ + ch] = s * 0.0625f;
}

// ---------------- agent attention v3: MFMA flash, one block per (b,h) -------
#define AKS_ 104
#define VTS_ 136
__global__ __launch_bounds__(256) void agent_attn_mfma_kernel(
    const float* __restrict__ agent, const ushort_t* __restrict__ qkvb,
    const float* __restrict__ abias, float* __restrict__ agent_v) {
  __shared__ ushort_t A_lds[64 * AKS_];
  __shared__ ushort_t K_lds[112 * AKS_];
  __shared__ ushort_t Vt_lds[80 * VTS_];
  __shared__ ushort_t P_lds[4][16 * VTS_];
  const int tid = threadIdx.x;
  const int lane = tid & 63, wid = tid >> 6;
  const int l16 = lane & 15, lq = lane >> 4;
  const int b = blockIdx.x >> 3, h = blockIdx.x & 7;

  for (int i = tid; i < 64 * AKS_; i += 256) A_lds[i] = 0;
  for (int i = tid; i < 112 * 32; i += 256) {
    int r = i >> 5, cc = 72 + (i & 31);
    K_lds[r * AKS_ + cc] = 0;
  }
  for (int i = tid; i < 80 * VTS_; i += 256) Vt_lds[i] = 0;
  for (int i = tid; i < 4 * 16 * 24; i += 256) {
    int w = i / (16 * 24), rest = i % (16 * 24);
    int r = rest / 24, cc = 112 + rest % 24;
    P_lds[w][r * VTS_ + cc] = 0;
  }
  for (int i = tid; i < AGENT_ * HD_; i += 256) {
    int a = i / HD_, d = i % HD_;
    A_lds[a * AKS_ + d] = f2bf(agent[((size_t)b * AGENT_ + a) * C_ + h * HD_ + d]);
  }

  int srow[4], scol[4]; bool sval[4];
  #pragma unroll
  for (int i = 0; i < 4; ++i) {
    int idx = tid + i * 256;
    srow[i] = idx / 9; scol[i] = idx % 9;
    sval[i] = idx < 1008;
  }
  const ushort_t* kbase = qkvb + (size_t)b * N_ * QKVW_ + C_ + h * HD_;
  const ushort_t* vbase = qkvb + (size_t)b * N_ * QKVW_ + 2 * C_ + h * HD_;

  u16x8 kreg[4], vreg[4];
  #pragma unroll
  for (int i = 0; i < 4; ++i) {
    if (sval[i]) {
      kreg[i] = *(const u16x8*)(kbase + (size_t)srow[i] * QKVW_ + scol[i] * 8);
      vreg[i] = *(const u16x8*)(vbase + (size_t)srow[i] * QKVW_ + scol[i] * 8);
    }
  }
  #pragma unroll
  for (int i = 0; i < 4; ++i) {
    if (sval[i]) {
      *(u16x8*)&K_lds[srow[i] * AKS_ + scol[i] * 8] = kreg[i];
      #pragma unroll
      for (int e = 0; e < 8; ++e)
        Vt_lds[(scol[i] * 8 + e) * VTS_ + srow[i]] = vreg[i][e];
    }
  }
  __syncthreads();

  float m_r[4] = {-1e30f, -1e30f, -1e30f, -1e30f};
  float l_r[4] = {};
  f32x4 O[5] = {};
  const float* bias_base[4];
  #pragma unroll
  for (int r = 0; r < 4; ++r) {
    int a = wid * 16 + lq * 4 + r;
    a = min(a, AGENT_ - 1);
    bias_base[r] = abias + ((size_t)h * AGENT_ + a) * N_;
  }

  for (int c = 0; c < 7; ++c) {
    if (c < 6) {
      const size_t off = (size_t)(c + 1) * 112 * QKVW_;
      #pragma unroll
      for (int i = 0; i < 4; ++i) {
        if (sval[i]) {
          kreg[i] = *(const u16x8*)(kbase + off + (size_t)srow[i] * QKVW_ + scol[i] * 8);
          vreg[i] = *(const u16x8*)(vbase + off + (size_t)srow[i] * QKVW_ + scol[i] * 8);
        }
      }
    }
    f32x4 sacc[7] = {};
    #pragma unroll
    for (int ks = 0; ks < 3; ++ks) {
      bf16x8 af = *(const bf16x8*)&A_lds[(wid * 16 + l16) * AKS_ + ks * 32 + lq * 8];
      #pragma unroll
      for (int nt = 0; nt < 7; ++nt) {
        bf16x8 bf = *(const bf16x8*)&K_lds[(nt * 16 + l16) * AKS_ + ks * 32 + lq * 8];
        sacc[nt] = __builtin_amdgcn_mfma_f32_16x16x32_bf16(af, bf, sacc[nt], 0, 0, 0);
      }
    }
    float cmax[4] = {-1e30f, -1e30f, -1e30f, -1e30f};
    const int nb = c * 112 + l16;
    #pragma unroll
    for (int nt = 0; nt < 7; ++nt)
      #pragma unroll
      for (int r = 0; r < 4; ++r) {
        float lg = sacc[nt][r] * SCALE_ + bias_base[r][nb + nt * 16];
        sacc[nt][r] = lg;
        cmax[r] = fmaxf(cmax[r], lg);
      }
    #pragma unroll
    for (int off = 1; off < 16; off <<= 1)
      #pragma unroll
      for (int r = 0; r < 4; ++r)
        cmax[r] = fmaxf(cmax[r], __shfl_xor(cmax[r], off));
    float scl[4], rs[4];
    #pragma unroll
    for (int r = 0; r < 4; ++r) {
      float nm = fmaxf(m_r[r], cmax[r]);
      scl[r] = __expf(m_r[r] - nm);
      m_r[r] = nm;
      rs[r] = 0.f;
    }
    #pragma unroll
    for (int nt = 0; nt < 7; ++nt)
      #pragma unroll
      for (int r = 0; r < 4; ++r) {
        float p = __expf(sacc[nt][r] - m_r[r]);
        rs[r] += p;
        P_lds[wid][(lq * 4 + r) * VTS_ + nt * 16 + l16] = f2bf(p);
      }
    #pragma unroll
    for (int off = 1; off < 16; off <<= 1)
      #pragma unroll
      for (int r = 0; r < 4; ++r)
        rs[r] += __shfl_xor(rs[r], off);
    #pragma unroll
    for (int r = 0; r < 4; ++r) l_r[r] = l_r[r] * scl[r] + rs[r];
    #pragma unroll
    for (int nt = 0; nt < 5; ++nt)
      #pragma unroll
      for (int r = 0; r < 4; ++r) O[nt][r] *= scl[r];
    #pragma unroll
    for (int ks = 0; ks < 4; ++ks) {
      bf16x8 pf = *(const bf16x8*)&P_lds[wid][l16 * VTS_ + ks * 32 + lq * 8];
      #pragma unroll
      for (int nt = 0; nt < 5; ++nt) {
        bf16x8 vf = *(const bf16x8*)&Vt_lds[(nt * 16 + l16) * VTS_ + ks * 32 + lq * 8];
        O[nt] = __builtin_amdgcn_mfma_f32_16x16x32_bf16(pf, vf, O[nt], 0, 0, 0);
      }
    }
    __syncthreads();
    if (c < 6) {
      #pragma unroll
      for (int i = 0; i < 4; ++i) {
        if (sval[i]) {
          *(u16x8*)&K_lds[srow[i] * AKS_ + scol[i] * 8] = kreg[i];
          #pragma unroll
          for (int e = 0; e < 8; ++e)
            Vt_lds[(scol[i] * 8 + e) * VTS_ + srow[i]] = vreg[i][e];
        }
      }
      __syncthreads();
    }
  }
  float inv[4];
  #pragma unroll
  for (int r = 0; r < 4; ++r) inv[r] = 1.f / l_r[r];
  #pragma unroll
  for (int nt = 0; nt < 5; ++nt) {
    int d = nt * 16 + l16;
    if (d >= HD_) continue;
    #pragma unroll
    for (int r = 0; r < 4; ++r) {
      int a = wid * 16 + lq * 4 + r;
      if (a < AGENT_)
        agent_v[(((size_t)b * HEADS_ + h) * AGENT_ + a) * HD_ + d] = O[nt][r] * inv[r];
    }
  }
}

// ---------------- q attention (round-11 proven form) ----------------
__global__ __launch_bounds__(256) void q_attn_kernel(
    const ushort_t* __restrict__ qkvb, const float* __restrict__ agent,
    const float* __restrict__ agent_v, const float* __restrict__ qbias,
    float* __restrict__ xf) {
  __shared__ float ag_t[HD_ * 52];
  __shared__ float av_t[HD_ * 52];
  const int tid = threadIdx.x;
  const int h = blockIdx.y, b = blockIdx.z;
  for (int t = tid; t < AGENT_ * HD_; t += 256) {
    int a = t / HD_, d = t % HD_;
    ag_t[d * 52 + a] = agent[((size_t)b * AGENT_ + a) * C_ + h * HD_ + d];
    av_t[d * 52 + a] = agent_v[(((size_t)b * HEADS_ + h) * AGENT_ + a) * HD_ + d];
  }
  __syncthreads();
  const int n = blockIdx.x * 256 + tid;
  if (n >= N_) return;
  const ushort_t* qp = qkvb + ((size_t)b * N_ + n) * QKVW_ + h * HD_;
  const float* qb = qbias + ((size_t)h * N_ + n) * AGENT_;
  float lg[AGENT_];
  #pragma unroll
  for (int a = 0; a < AGENT_; ++a) lg[a] = qb[a];
  for (int d = 0; d < HD_; ++d) {
    float qd = bf2f(qp[d]) * SCALE_;
    #pragma unroll
    for (int a = 0; a < AGENT_; ++a) lg[a] += qd * ag_t[d * 52 + a];
  }
  float mx = -1e30f;
  #pragma unroll
  for (int a = 0; a < AGENT_; ++a) mx = fmaxf(mx, lg[a]);
  float s = 0.f;
  #pragma unroll
  for (int a = 0; a < AGENT_; ++a) { lg[a] = __expf(lg[a] - mx); s += lg[a]; }
  float inv = 1.f / s;
  #pragma unroll
  for (int a = 0; a < AGENT_; ++a) lg[a] *= inv;
  float* op = xf + ((size_t)b * N_ + n) * C_ + h * HD_;
  for (int d = 0; d < HD_; ++d) {
    float acc = 0.f;
    #pragma unroll
    for (int a = 0; a < AGENT_; ++a) acc += lg[a] * av_t[d * 52 + a];
    op[d] = acc;
  }
}

// ---------------- depthwise conv + BN + ReLU (2ch/thread, XCD swizzle) ------
__global__ __launch_bounds__(288) void dwc_kernel(
    const ushort_t* __restrict__ qkvb, const float* __restrict__ w,
    const float* __restrict__ bias, const float* __restrict__ gamma,
    const float* __restrict__ beta, const float* __restrict__ mean,
    const float* __restrict__ var, float* __restrict__ xf) {
  int lin = blockIdx.x;
  const int bn = (lin & 7) * 3136 + (lin >> 3);   // 25088 = 8*3136, bijective
  const int b = bn / N_, n = bn % N_;
  const int y = n / W_, x = n % W_;
  const int c0 = threadIdx.x * 2;
  float a0 = 0.f, a1 = 0.f;
  #pragma unroll
  for (int ky = 0; ky < 3; ++ky) {
    int yy = y + ky - 1;
    if (yy < 0 || yy >= H_) continue;
    #pragma unroll
    for (int kx = 0; kx < 3; ++kx) {
      int xx = x + kx - 1;
      if (xx < 0 || xx >= W_) continue;
      unsigned v = *(const unsigned*)(qkvb + ((size_t)b * N_ + yy * W_ + xx) * QKVW_ + 2 * C_ + c0);
      a0 += w[c0 * 9 + ky * 3 + kx] * bf2f((ushort_t)(v & 0xffffu));
      a1 += w[(c0 + 1) * 9 + ky * 3 + kx] * bf2f((ushort_t)(v >> 16));
    }
  }
  float s0 = gamma[c0] * rsqrtf(var[c0] + 1e-5f);
  float s1 = gamma[c0 + 1] * rsqrtf(var[c0 + 1] + 1e-5f);
  float r0 = fmaxf((a0 + bias[c0] - mean[c0]) * s0 + beta[c0], 0.f);
  float r1 = fmaxf((a1 + bias[c0 + 1] - mean[c0 + 1]) * s1 + beta[c0 + 1], 0.f);
  float2* xp = (float2*)&xf[(size_t)bn * C_ + c0];
  float2 old = *xp;
  old.x += r0; old.y += r1;
  *xp = old;
}

extern "C" void kernel_launch(void* const* d_in, const int* in_sizes, int n_in,
                              void* d_out, int out_size, void* d_ws, size_t ws_size,
                              hipStream_t stream) {
  const float* x        = (const float*)d_in[0];
  const float* Wq       = (const float*)d_in[3];
  const float* Wkv      = (const float*)d_in[4];
  const float* an_bias  = (const float*)d_in[5];
  const float* na_bias  = (const float*)d_in[6];
  const float* ah_bias  = (const float*)d_in[7];
  const float* aw_bias  = (const float*)d_in[8];
  const float* ha_bias  = (const float*)d_in[9];
  const float* wa_bias  = (const float*)d_in[10];
  const float* dwc_w    = (const float*)d_in[11];
  const float* dwc_b    = (const float*)d_in[12];
  const float* bn_gamma = (const float*)d_in[13];
  const float* bn_beta  = (const float*)d_in[14];
  const float* bn_mean  = (const float*)d_in[15];
  const float* bn_var   = (const float*)d_in[16];
  const float* base_w   = (const float*)d_in[17];
  const float* spline_w = (const float*)d_in[18];
  const float* spline_s = (const float*)d_in[19];

  char* ws = (char*)d_ws;
  ushort_t* qkvb   = (ushort_t*)(ws + 0);
  ushort_t* xbf    = (ushort_t*)(ws + 86704128);
  ushort_t* wfrag  = (ushort_t*)(ws + 115605504);
  ushort_t* bfrag  = (ushort_t*)(ws + 117596160);
  float* agent     = (float*)(ws + 123568128);
  float* agent_v   = (float*)(ws + 127180800);
  float* abias     = (float*)(ws + 130793472);
  float* qbias     = (float*)(ws + 132022784);
  float* xf        = (float*)(ws + 133252096);
  float* out       = (float*)d_out;

  prep_kernel<<<dim3(PREP_TOTAL_), dim3(256), 0, stream>>>(
      x, xbf, Wq, Wkv, wfrag, base_w, spline_w, spline_s, bfrag,
      an_bias, na_bias, ah_bias, aw_bias, ha_bias, wa_bias, abias, qbias);
  mfma_qkv_kernel<<<dim3(1764), dim3(512), 0, stream>>>(xbf, wfrag, qkvb);
  agent_pool_kernel<<<dim3(B_ * AGENT_), dim3(C_), 0, stream>>>(qkvb, agent);
  agent_attn_mfma_kernel<<<dim3(B_ * HEADS_), dim3(256), 0, stream>>>(
      agent, qkvb, abias, agent_v);
  q_attn_kernel<<<dim3(4, HEADS_, B_), dim3(256), 0, stream>>>(
      qkvb, agent, agent_v, qbias, xf);
  dwc_kernel<<<dim3(M_), dim3(288), 0, stream>>>(
      qkvb, dwc_w, dwc_b, bn_gamma, bn_beta, bn_mean, bn_var, xf);
  kan_mfma_kernel<<<dim3(588), dim3(512), 0, stream>>>(xf, bfrag, out);
}